// Round 1
// baseline (3901.353 us; speedup 1.0000x reference)
//
#include <hip/hip_runtime.h>

#define N_NODES 50000
#define N_EDGES 200000
#define D 200
#define D4 50           // D/4 float4 chunks
#define NLAYERS 10
#define NGRAPH 2500
#define EPS 1e-5f

// ---------------- CSR build (per launch; ws is re-poisoned every call) -------

__global__ void count_kernel(const int* __restrict__ dst, int* __restrict__ counts) {
    int e = blockIdx.x * 256 + threadIdx.x;
    if (e < N_EDGES) atomicAdd(&counts[dst[e]], 1);
}

__global__ void scan1_kernel(const int* __restrict__ counts, int* __restrict__ psum) {
    __shared__ int s[256];
    int idx = blockIdx.x * 256 + threadIdx.x;
    s[threadIdx.x] = (idx < N_NODES) ? counts[idx] : 0;
    __syncthreads();
    for (int off = 128; off > 0; off >>= 1) {
        if (threadIdx.x < off) s[threadIdx.x] += s[threadIdx.x + off];
        __syncthreads();
    }
    if (threadIdx.x == 0) psum[blockIdx.x] = s[0];
}

__global__ void scan2_kernel(const int* __restrict__ psum, int* __restrict__ poff, int nchunk) {
    __shared__ int s[256];
    int t = threadIdx.x;
    int v = (t < nchunk) ? psum[t] : 0;
    s[t] = v;
    __syncthreads();
    for (int off = 1; off < 256; off <<= 1) {
        int xv = (t >= off) ? s[t - off] : 0;
        __syncthreads();
        s[t] += xv;
        __syncthreads();
    }
    if (t < nchunk) poff[t] = s[t] - v;   // exclusive
}

__global__ void scan3_kernel(const int* __restrict__ counts, const int* __restrict__ poff,
                             int* __restrict__ row_start, int* __restrict__ cursor) {
    __shared__ int s[256];
    int t = threadIdx.x;
    int idx = blockIdx.x * 256 + t;
    int v = (idx < N_NODES) ? counts[idx] : 0;
    s[t] = v;
    __syncthreads();
    for (int off = 1; off < 256; off <<= 1) {
        int xv = (t >= off) ? s[t - off] : 0;
        __syncthreads();
        s[t] += xv;
        __syncthreads();
    }
    if (idx < N_NODES) {
        int rs = poff[blockIdx.x] + s[t] - v;
        row_start[idx] = rs;
        cursor[idx] = rs;
    }
    if (blockIdx.x == 0 && t == 0) row_start[N_NODES] = N_EDGES;
}

__global__ void scatter_kernel(const int* __restrict__ dst, int* __restrict__ cursor,
                               int* __restrict__ edge_list) {
    int e = blockIdx.x * 256 + threadIdx.x;
    if (e < N_EDGES) {
        int p = atomicAdd(&cursor[dst[e]], 1);
        edge_list[p] = e;
    }
}

// ---------------- graph boundaries for mean-pool (batch is sorted) -----------

__global__ void bounds_kernel(const int* __restrict__ batch, int* __restrict__ gstart) {
    int g = blockIdx.x * 256 + threadIdx.x;
    if (g > NGRAPH) return;
    if (g == NGRAPH) { gstart[NGRAPH] = N_NODES; return; }
    int lo = 0, hi = N_NODES;
    while (lo < hi) { int mid = (lo + hi) >> 1; if (batch[mid] < g) lo = mid + 1; else hi = mid; }
    gstart[g] = lo;
}

// ---------------- node feature init -----------------------------------------

__global__ void embed_kernel(const int* __restrict__ x, const float* __restrict__ emb1,
                             const float* __restrict__ emb2, float* __restrict__ h) {
    int idx = blockIdx.x * 256 + threadIdx.x;
    if (idx >= N_NODES * D4) return;
    int node = idx / D4;
    int c = (idx % D4) * 4;
    int a = x[node * 2], b = x[node * 2 + 1];
    float4 v1 = *(const float4*)(emb1 + (size_t)a * D + c);
    float4 v2 = *(const float4*)(emb2 + (size_t)b * D + c);
    float4 o;
    o.x = v1.x + v2.x; o.y = v1.y + v2.y; o.z = v1.z + v2.z; o.w = v1.w + v2.w;
    *(float4*)(h + (size_t)node * D + c) = o;
}

// ---------------- message + aggregate (gather over CSR, incl. self loop) -----

__global__ void aggregate_kernel(const float* __restrict__ h,
                                 const float* __restrict__ e1, const float* __restrict__ e2,
                                 const int* __restrict__ row_start, const int* __restrict__ edge_list,
                                 const int* __restrict__ src, const int* __restrict__ edge_attr,
                                 float* __restrict__ aggr) {
    __shared__ float t1[5 * D];
    __shared__ float t2[3 * D];
    for (int i = threadIdx.x; i < 5 * D; i += 256) t1[i] = e1[i];
    for (int i = threadIdx.x; i < 3 * D; i += 256) t2[i] = e2[i];
    __syncthreads();
    int idx = blockIdx.x * 256 + threadIdx.x;
    if (idx >= N_NODES * D4) return;
    int node = idx / D4;
    int c = (idx % D4) * 4;
    float4 acc = *(const float4*)(h + (size_t)node * D + c);
    // self-loop embedding: edge_emb1[4] + edge_emb2[0]
    acc.x += t1[4 * D + c + 0] + t2[c + 0];
    acc.y += t1[4 * D + c + 1] + t2[c + 1];
    acc.z += t1[4 * D + c + 2] + t2[c + 2];
    acc.w += t1[4 * D + c + 3] + t2[c + 3];
    int jb = row_start[node], je = row_start[node + 1];
    for (int j = jb; j < je; ++j) {
        int e = edge_list[j];
        int s = src[e];
        int2 eav = *(const int2*)(edge_attr + 2 * e);
        float4 hv = *(const float4*)(h + (size_t)s * D + c);
        const float* p1 = t1 + eav.x * D + c;
        const float* p2 = t2 + eav.y * D + c;
        acc.x += hv.x + p1[0] + p2[0];
        acc.y += hv.y + p1[1] + p2[1];
        acc.z += hv.z + p1[2] + p2[2];
        acc.w += hv.w + p1[3] + p2[3];
    }
    *(float4*)(aggr + (size_t)node * D + c) = acc;
}

// ---------------- fp32 tiled GEMM: C[M,Nc] = A[M,K] @ W[K,Nc] + bias ---------

#define BM 128
#define BN 64
#define BK 8

__global__ __launch_bounds__(256) void gemm_kernel(const float* __restrict__ A,
                                                   const float* __restrict__ W,
                                                   const float* __restrict__ bias,
                                                   float* __restrict__ C,
                                                   int M, int K, int Nc, int relu) {
    __shared__ float As[BK][BM];
    __shared__ float Bs[BK][BN];
    int tid = threadIdx.x;
    int bm = blockIdx.x * BM;
    int bn = blockIdx.y * BN;
    int tx = tid & 15, ty = tid >> 4;

    float acc[8][4];
#pragma unroll
    for (int i = 0; i < 8; ++i)
#pragma unroll
        for (int j = 0; j < 4; ++j) acc[i][j] = 0.f;

    int ar = tid >> 1;            // 0..127
    int ak = (tid & 1) << 2;      // 0 or 4
    int bk = tid >> 5;            // 0..7
    int bcol = (tid & 31) << 1;   // 0..62

    for (int k0 = 0; k0 < K; k0 += BK) {
        float4 av = {0.f, 0.f, 0.f, 0.f};
        int row = bm + ar;
        if (row < M) av = *(const float4*)(A + (size_t)row * K + k0 + ak);
        As[ak + 0][ar] = av.x; As[ak + 1][ar] = av.y;
        As[ak + 2][ar] = av.z; As[ak + 3][ar] = av.w;
        float2 bv = {0.f, 0.f};
        int col = bn + bcol;
        if (col < Nc) bv = *(const float2*)(W + (size_t)(k0 + bk) * Nc + col);
        Bs[bk][bcol] = bv.x; Bs[bk][bcol + 1] = bv.y;
        __syncthreads();
#pragma unroll
        for (int kk = 0; kk < BK; ++kk) {
            float a[8], b[4];
            *(float4*)(a)     = *(const float4*)(&As[kk][ty * 8]);
            *(float4*)(a + 4) = *(const float4*)(&As[kk][ty * 8 + 4]);
            *(float4*)(b)     = *(const float4*)(&Bs[kk][tx * 4]);
#pragma unroll
            for (int i = 0; i < 8; ++i)
#pragma unroll
                for (int j = 0; j < 4; ++j) acc[i][j] = fmaf(a[i], b[j], acc[i][j]);
        }
        __syncthreads();
    }

#pragma unroll
    for (int i = 0; i < 8; ++i) {
        int row = bm + ty * 8 + i;
        if (row < M) {
            int col = bn + tx * 4;
            if (col < Nc) {  // Nc % 4 == 0, col % 4 == 0 -> full float4 valid
                float4 bb = *(const float4*)(bias + col);
                float4 v;
                v.x = acc[i][0] + bb.x; v.y = acc[i][1] + bb.y;
                v.z = acc[i][2] + bb.z; v.w = acc[i][3] + bb.w;
                if (relu) {
                    v.x = fmaxf(v.x, 0.f); v.y = fmaxf(v.y, 0.f);
                    v.z = fmaxf(v.z, 0.f); v.w = fmaxf(v.w, 0.f);
                }
                *(float4*)(C + (size_t)row * Nc + col) = v;
            }
        }
    }
}

// ---------------- BatchNorm (training-mode batch stats) ----------------------

#define BN_ROWS 250   // 200 blocks * 250 rows = 50000

__global__ void bn_stats_kernel(const float* __restrict__ h2, float* __restrict__ stats) {
    int c = threadIdx.x;
    if (c >= D) return;
    int r0 = blockIdx.x * BN_ROWS;
    float s = 0.f, q = 0.f;
    for (int r = r0; r < r0 + BN_ROWS; ++r) {
        float v = h2[(size_t)r * D + c];
        s += v; q += v * v;
    }
    atomicAdd(&stats[c], s);
    atomicAdd(&stats[D + c], q);
}

__global__ void bn_norm_kernel(const float* __restrict__ h2, float* __restrict__ hout,
                               const float* __restrict__ stats, const float* __restrict__ gamma,
                               const float* __restrict__ beta, int relu) {
    int idx = blockIdx.x * 256 + threadIdx.x;
    if (idx >= N_NODES * D4) return;
    int node = idx / D4;
    int c = (idx % D4) * 4;
    const float inv = 1.0f / (float)N_NODES;
    float4 v  = *(const float4*)(h2 + (size_t)node * D + c);
    float4 sm = *(const float4*)(stats + c);
    float4 sq = *(const float4*)(stats + D + c);
    float4 gm = *(const float4*)(gamma + c);
    float4 bt = *(const float4*)(beta + c);
    float m, var, sc, o;
    m = sm.x * inv; var = sq.x * inv - m * m; sc = gm.x / sqrtf(var + EPS);
    o = (v.x - m) * sc + bt.x; v.x = relu ? fmaxf(o, 0.f) : o;
    m = sm.y * inv; var = sq.y * inv - m * m; sc = gm.y / sqrtf(var + EPS);
    o = (v.y - m) * sc + bt.y; v.y = relu ? fmaxf(o, 0.f) : o;
    m = sm.z * inv; var = sq.z * inv - m * m; sc = gm.z / sqrtf(var + EPS);
    o = (v.z - m) * sc + bt.z; v.z = relu ? fmaxf(o, 0.f) : o;
    m = sm.w * inv; var = sq.w * inv - m * m; sc = gm.w / sqrtf(var + EPS);
    o = (v.w - m) * sc + bt.w; v.w = relu ? fmaxf(o, 0.f) : o;
    *(float4*)(hout + (size_t)node * D + c) = v;
}

// ---------------- global mean pool -------------------------------------------

__global__ void pool_kernel(const float* __restrict__ h, const int* __restrict__ gstart,
                            float* __restrict__ hg) {
    int idx = blockIdx.x * 256 + threadIdx.x;
    if (idx >= NGRAPH * D4) return;
    int g = idx / D4;
    int c = (idx % D4) * 4;
    int s = gstart[g], e = gstart[g + 1];
    float4 acc = {0.f, 0.f, 0.f, 0.f};
    for (int r = s; r < e; ++r) {
        float4 v = *(const float4*)(h + (size_t)r * D + c);
        acc.x += v.x; acc.y += v.y; acc.z += v.z; acc.w += v.w;
    }
    float inv = 1.0f / fmaxf((float)(e - s), 1.0f);
    acc.x *= inv; acc.y *= inv; acc.z *= inv; acc.w *= inv;
    *(float4*)(hg + (size_t)g * D + c) = acc;
}

// ---------------- launch ------------------------------------------------------

extern "C" void kernel_launch(void* const* d_in, const int* in_sizes, int n_in,
                              void* d_out, int out_size, void* d_ws, size_t ws_size,
                              hipStream_t stream) {
    const int*   x       = (const int*)d_in[0];
    const int*   ei      = (const int*)d_in[1];
    const int*   ea      = (const int*)d_in[2];
    const int*   batch   = (const int*)d_in[3];
    const float* x_emb1  = (const float*)d_in[4];
    const float* x_emb2  = (const float*)d_in[5];
    const float* e1w     = (const float*)d_in[6];
    const float* e2w     = (const float*)d_in[7];
    const float* w1      = (const float*)d_in[8];
    const float* b1      = (const float*)d_in[9];
    const float* w2      = (const float*)d_in[10];
    const float* b2      = (const float*)d_in[11];
    const float* gamma   = (const float*)d_in[12];
    const float* beta    = (const float*)d_in[13];
    const float* feat_w  = (const float*)d_in[14];
    const float* feat_b  = (const float*)d_in[15];
    const float* out_w1  = (const float*)d_in[16];
    const float* out_b1  = (const float*)d_in[17];
    const float* out_w2  = (const float*)d_in[18];
    const float* out_b2  = (const float*)d_in[19];
    const int* src = ei;
    const int* dst = ei + N_EDGES;

    char* p = (char*)d_ws;
    auto alloc = [&](size_t bytes) -> void* {
        void* r = (void*)p;
        p += (bytes + 255) & ~(size_t)255;
        return r;
    };
    float* h         = (float*)alloc((size_t)N_NODES * D * 4);       // 40 MB
    float* aggr      = (float*)alloc((size_t)N_NODES * D * 4);       // 40 MB (also reused as h2)
    float* h1        = (float*)alloc((size_t)N_NODES * 2 * D * 4);   // 80 MB
    int*   counts    = (int*)alloc(N_NODES * 4);
    int*   row_start = (int*)alloc((N_NODES + 1) * 4);
    int*   cursor    = (int*)alloc(N_NODES * 4);
    int*   edge_list = (int*)alloc(N_EDGES * 4);
    int*   psum      = (int*)alloc(256 * 4);
    int*   poff      = (int*)alloc(256 * 4);
    int*   gstart    = (int*)alloc((NGRAPH + 1) * 4);
    float* stats     = (float*)alloc(2 * D * 4);
    float* hg        = (float*)alloc((size_t)NGRAPH * D * 4);
    float* tbuf      = (float*)alloc((size_t)NGRAPH * D * 4);
    float* outf      = (float*)d_out;

    const int NCHUNK = (N_NODES + 255) / 256;   // 196

    // CSR build + graph bounds
    hipMemsetAsync(counts, 0, N_NODES * 4, stream);
    count_kernel<<<(N_EDGES + 255) / 256, 256, 0, stream>>>(dst, counts);
    scan1_kernel<<<NCHUNK, 256, 0, stream>>>(counts, psum);
    scan2_kernel<<<1, 256, 0, stream>>>(psum, poff, NCHUNK);
    scan3_kernel<<<NCHUNK, 256, 0, stream>>>(counts, poff, row_start, cursor);
    scatter_kernel<<<(N_EDGES + 255) / 256, 256, 0, stream>>>(dst, cursor, edge_list);
    bounds_kernel<<<(NGRAPH + 1 + 255) / 256, 256, 0, stream>>>(batch, gstart);

    const int nthreads_nd = N_NODES * D4;
    embed_kernel<<<(nthreads_nd + 255) / 256, 256, 0, stream>>>(x, x_emb1, x_emb2, h);

    dim3 g1((N_NODES + BM - 1) / BM, (2 * D + BN - 1) / BN);   // 391 x 7
    dim3 g2((N_NODES + BM - 1) / BM, (D + BN - 1) / BN);       // 391 x 4
    for (int l = 0; l < NLAYERS; ++l) {
        aggregate_kernel<<<(nthreads_nd + 255) / 256, 256, 0, stream>>>(
            h, e1w + (size_t)l * 5 * D, e2w + (size_t)l * 3 * D,
            row_start, edge_list, src, ea, aggr);
        gemm_kernel<<<g1, 256, 0, stream>>>(aggr, w1 + (size_t)l * D * 2 * D,
                                            b1 + (size_t)l * 2 * D, h1, N_NODES, D, 2 * D, 1);
        gemm_kernel<<<g2, 256, 0, stream>>>(h1, w2 + (size_t)l * 2 * D * D,
                                            b2 + (size_t)l * D, aggr, N_NODES, 2 * D, D, 0);
        hipMemsetAsync(stats, 0, 2 * D * 4, stream);
        bn_stats_kernel<<<200, 256, 0, stream>>>(aggr, stats);
        bn_norm_kernel<<<(nthreads_nd + 255) / 256, 256, 0, stream>>>(
            aggr, h, stats, gamma + (size_t)l * D, beta + (size_t)l * D,
            (l < NLAYERS - 1) ? 1 : 0);
    }

    pool_kernel<<<(NGRAPH * D4 + 255) / 256, 256, 0, stream>>>(h, gstart, hg);

    dim3 gp((NGRAPH + BM - 1) / BM, (D + BN - 1) / BN);        // 20 x 4
    gemm_kernel<<<gp, 256, 0, stream>>>(hg, feat_w, feat_b, outf, NGRAPH, D, D, 0);
    gemm_kernel<<<gp, 256, 0, stream>>>(outf, out_w1, out_b1, tbuf, NGRAPH, D, D, 1);
    dim3 go((NGRAPH + BM - 1) / BM, (100 + BN - 1) / BN);      // 20 x 2
    gemm_kernel<<<go, 256, 0, stream>>>(tbuf, out_w2, out_b2, outf + (size_t)NGRAPH * D,
                                        NGRAPH, D, 100, 0);
    hipMemcpyAsync(outf + (size_t)NGRAPH * D + (size_t)NGRAPH * 100,
                   outf + (size_t)NGRAPH * D,
                   (size_t)NGRAPH * 100 * 4, hipMemcpyDeviceToDevice, stream);
}

// Round 2
// 2747.230 us; speedup vs baseline: 1.4201x; 1.4201x over previous
//
#include <hip/hip_runtime.h>

#define N_NODES 50000
#define N_EDGES 200000
#define D 200
#define NLAYERS 10
#define NGRAPH 2500
#define EPS 1e-5f

typedef unsigned short u16;
typedef __attribute__((ext_vector_type(8))) __bf16 bf16x8;
typedef __attribute__((ext_vector_type(4))) float f32x4;

// fp32 -> bf16 RNE
__device__ __forceinline__ u16 f2bf_rne(float x) {
    union { float f; unsigned u; } c; c.f = x;
    unsigned r = c.u + 0x7FFF + ((c.u >> 16) & 1);
    return (u16)(r >> 16);
}
__device__ __forceinline__ void split_bf16(float x, u16& h, u16& l) {
    h = f2bf_rne(x);
    union { unsigned u; float f; } c; c.u = ((unsigned)h) << 16;
    l = f2bf_rne(x - c.f);
}

// ---------------- CSR build -------------------------------------------------

__global__ void count_kernel(const int* __restrict__ dst, int* __restrict__ counts) {
    int e = blockIdx.x * 256 + threadIdx.x;
    if (e < N_EDGES) atomicAdd(&counts[dst[e]], 1);
}

__global__ void scan1_kernel(const int* __restrict__ counts, int* __restrict__ psum) {
    __shared__ int s[256];
    int idx = blockIdx.x * 256 + threadIdx.x;
    s[threadIdx.x] = (idx < N_NODES) ? counts[idx] : 0;
    __syncthreads();
    for (int off = 128; off > 0; off >>= 1) {
        if (threadIdx.x < off) s[threadIdx.x] += s[threadIdx.x + off];
        __syncthreads();
    }
    if (threadIdx.x == 0) psum[blockIdx.x] = s[0];
}

__global__ void scan2_kernel(const int* __restrict__ psum, int* __restrict__ poff, int nchunk) {
    __shared__ int s[256];
    int t = threadIdx.x;
    int v = (t < nchunk) ? psum[t] : 0;
    s[t] = v;
    __syncthreads();
    for (int off = 1; off < 256; off <<= 1) {
        int xv = (t >= off) ? s[t - off] : 0;
        __syncthreads();
        s[t] += xv;
        __syncthreads();
    }
    if (t < nchunk) poff[t] = s[t] - v;
}

__global__ void scan3_kernel(const int* __restrict__ counts, const int* __restrict__ poff,
                             int* __restrict__ row_start, int* __restrict__ cursor) {
    __shared__ int s[256];
    int t = threadIdx.x;
    int idx = blockIdx.x * 256 + t;
    int v = (idx < N_NODES) ? counts[idx] : 0;
    s[t] = v;
    __syncthreads();
    for (int off = 1; off < 256; off <<= 1) {
        int xv = (t >= off) ? s[t - off] : 0;
        __syncthreads();
        s[t] += xv;
        __syncthreads();
    }
    if (idx < N_NODES) {
        int rs = poff[blockIdx.x] + s[t] - v;
        row_start[idx] = rs;
        cursor[idx] = rs;
    }
    if (blockIdx.x == 0 && t == 0) row_start[N_NODES] = N_EDGES;
}

__global__ void scatter_kernel(const int* __restrict__ dst, int* __restrict__ cursor,
                               int* __restrict__ edge_list) {
    int e = blockIdx.x * 256 + threadIdx.x;
    if (e < N_EDGES) {
        int p = atomicAdd(&cursor[dst[e]], 1);
        edge_list[p] = e;
    }
}

__global__ void bounds_kernel(const int* __restrict__ batch, int* __restrict__ gstart) {
    int g = blockIdx.x * 256 + threadIdx.x;
    if (g > NGRAPH) return;
    if (g == NGRAPH) { gstart[NGRAPH] = N_NODES; return; }
    int lo = 0, hi = N_NODES;
    while (lo < hi) { int mid = (lo + hi) >> 1; if (batch[mid] < g) lo = mid + 1; else hi = mid; }
    gstart[g] = lo;
}

// ---------------- weight prep: transpose + pad + bf16 hi/lo split ------------
// Wt1: [L][448][224]  (rows = output col n of W1, cols = k)
// Wt2: [L][256][416]

__global__ void prep_w1_kernel(const float* __restrict__ w, u16* __restrict__ wh, u16* __restrict__ wl) {
    int idx = blockIdx.x * 256 + threadIdx.x;
    if (idx >= NLAYERS * 448 * 224) return;
    int k = idx % 224;
    int n = (idx / 224) % 448;
    int l = idx / (224 * 448);
    float v = (k < 200 && n < 400) ? w[((size_t)l * 200 + k) * 400 + n] : 0.f;
    u16 hh, ll; split_bf16(v, hh, ll);
    wh[idx] = hh; wl[idx] = ll;
}

__global__ void prep_w2_kernel(const float* __restrict__ w, u16* __restrict__ wh, u16* __restrict__ wl) {
    int idx = blockIdx.x * 256 + threadIdx.x;
    if (idx >= NLAYERS * 256 * 416) return;
    int k = idx % 416;
    int n = (idx / 416) % 256;
    int l = idx / (416 * 256);
    float v = (k < 400 && n < 200) ? w[((size_t)l * 400 + k) * 200 + n] : 0.f;
    u16 hh, ll; split_bf16(v, hh, ll);
    wh[idx] = hh; wl[idx] = ll;
}

// ---------------- node feature init ------------------------------------------

__global__ void embed_kernel(const int* __restrict__ x, const float* __restrict__ emb1,
                             const float* __restrict__ emb2, float* __restrict__ h) {
    int idx = blockIdx.x * 256 + threadIdx.x;
    if (idx >= N_NODES * 50) return;
    int node = idx / 50;
    int c = (idx % 50) * 4;
    int a = x[node * 2], b = x[node * 2 + 1];
    float4 v1 = *(const float4*)(emb1 + (size_t)a * D + c);
    float4 v2 = *(const float4*)(emb2 + (size_t)b * D + c);
    float4 o;
    o.x = v1.x + v2.x; o.y = v1.y + v2.y; o.z = v1.z + v2.z; o.w = v1.w + v2.w;
    *(float4*)(h + (size_t)node * D + c) = o;
}

// ---------------- message + aggregate -> bf16 hi/lo padded [50048][224] ------

__global__ void aggregate_kernel(const float* __restrict__ h,
                                 const float* __restrict__ e1, const float* __restrict__ e2,
                                 const int* __restrict__ row_start, const int* __restrict__ edge_list,
                                 const int* __restrict__ src, const int* __restrict__ edge_attr,
                                 u16* __restrict__ Ah, u16* __restrict__ Al) {
    __shared__ float t1[5 * D];
    __shared__ float t2[3 * D];
    for (int i = threadIdx.x; i < 5 * D; i += 256) t1[i] = e1[i];
    for (int i = threadIdx.x; i < 3 * D; i += 256) t2[i] = e2[i];
    __syncthreads();
    int idx = blockIdx.x * 256 + threadIdx.x;
    if (idx >= N_NODES * 56) return;
    int node = idx / 56;
    int c = (idx % 56) * 4;
    size_t ob = (size_t)node * 224 + c;
    if (c >= 200) {  // K padding
        *(uint2*)(Ah + ob) = make_uint2(0u, 0u);
        *(uint2*)(Al + ob) = make_uint2(0u, 0u);
        return;
    }
    float4 acc = *(const float4*)(h + (size_t)node * D + c);
    acc.x += t1[4 * D + c + 0] + t2[c + 0];
    acc.y += t1[4 * D + c + 1] + t2[c + 1];
    acc.z += t1[4 * D + c + 2] + t2[c + 2];
    acc.w += t1[4 * D + c + 3] + t2[c + 3];
    int jb = row_start[node], je = row_start[node + 1];
    for (int j = jb; j < je; ++j) {
        int e = edge_list[j];
        int s = src[e];
        int2 eav = *(const int2*)(edge_attr + 2 * e);
        float4 hv = *(const float4*)(h + (size_t)s * D + c);
        const float* p1 = t1 + eav.x * D + c;
        const float* p2 = t2 + eav.y * D + c;
        acc.x += hv.x + p1[0] + p2[0];
        acc.y += hv.y + p1[1] + p2[1];
        acc.z += hv.z + p1[2] + p2[2];
        acc.w += hv.w + p1[3] + p2[3];
    }
    u16 h0, l0, h1v, l1, h2v, l2, h3v, l3;
    split_bf16(acc.x, h0, l0); split_bf16(acc.y, h1v, l1);
    split_bf16(acc.z, h2v, l2); split_bf16(acc.w, h3v, l3);
    ushort4 vh; vh.x = h0; vh.y = h1v; vh.z = h2v; vh.w = h3v;
    ushort4 vl; vl.x = l0; vl.y = l1; vl.z = l2; vl.w = l3;
    *(ushort4*)(Ah + ob) = vh;
    *(ushort4*)(Al + ob) = vl;
}

// ---------------- bf16x2 MFMA GEMM -------------------------------------------
// C[M,Nc] = A[M,Kpad] @ Wt[Nc,Kpad]^T + bias, A/Wt as bf16 hi+lo (3-term).
// Block tile 128x64, 4 waves (2x2), wave tile 64x32, K-step 32, 16x16x32 MFMA.
// LDS XOR swizzle: element offset(row,g) = row*32 + (g ^ ((row>>1)&3))*8.

template <int RELU, int WRITE_BF16>
__global__ __launch_bounds__(256) void gemm_mfma(
    const u16* __restrict__ Ah, const u16* __restrict__ Al,
    const u16* __restrict__ Bh, const u16* __restrict__ Bl,
    const float* __restrict__ bias,
    float* __restrict__ Cf, u16* __restrict__ Ch, u16* __restrict__ Cl,
    int M, int Kpad, int Nc, int NcPad, int KT)
{
    __shared__ alignas(16) u16 sAh[128 * 32];
    __shared__ alignas(16) u16 sAl[128 * 32];
    __shared__ alignas(16) u16 sBh[64 * 32];
    __shared__ alignas(16) u16 sBl[64 * 32];

    const int tid = threadIdx.x;
    const int lane = tid & 63;
    const int wid = tid >> 6;
    const int wm = wid >> 1, wn = wid & 1;
    const int lr = lane & 15, lg = lane >> 4;
    const int bm0 = blockIdx.x * 128;
    const int bn0 = blockIdx.y * 64;

    // staging: thread -> (row = tid>>2 [+64], data-granule gd = tid&3)
    const int r0 = tid >> 2;
    const int gd = tid & 3;
    const int slot = gd ^ ((r0 >> 1) & 3);
    const int lA0 = r0 * 32 + slot * 8;          // LDS elem offset, inst 0
    const int lA1 = lA0 + 64 * 32;               // inst 1 (rows 64..127)
    const size_t gA0 = (size_t)(bm0 + r0) * Kpad + gd * 8;
    const size_t gA1 = gA0 + (size_t)64 * Kpad;
    const size_t gB0 = (size_t)(bn0 + r0) * Kpad + gd * 8;

    f32x4 acc[4][2];
#pragma unroll
    for (int i = 0; i < 4; ++i)
#pragma unroll
        for (int j = 0; j < 2; ++j) acc[i][j] = (f32x4){0.f, 0.f, 0.f, 0.f};

    // fragment read offsets (elements)
    int aoff[4], boff[2];
#pragma unroll
    for (int fm = 0; fm < 4; ++fm) {
        int row = wm * 64 + fm * 16 + lr;
        aoff[fm] = row * 32 + ((lg ^ ((row >> 1) & 3)) * 8);
    }
#pragma unroll
    for (int fn = 0; fn < 2; ++fn) {
        int row = wn * 32 + fn * 16 + lr;
        boff[fn] = row * 32 + ((lg ^ ((row >> 1) & 3)) * 8);
    }

    uint4 rAh0, rAh1, rAl0, rAl1, rBh, rBl;
#define LOADT(K0)                                          \
    rAh0 = *(const uint4*)(Ah + gA0 + (K0));               \
    rAh1 = *(const uint4*)(Ah + gA1 + (K0));               \
    rAl0 = *(const uint4*)(Al + gA0 + (K0));               \
    rAl1 = *(const uint4*)(Al + gA1 + (K0));               \
    rBh  = *(const uint4*)(Bh + gB0 + (K0));               \
    rBl  = *(const uint4*)(Bl + gB0 + (K0));

    LOADT(0)
    for (int kt = 0; kt < KT; ++kt) {
        if (kt > 0) __syncthreads();          // previous compute done reading LDS
        *(uint4*)(sAh + lA0) = rAh0;
        *(uint4*)(sAh + lA1) = rAh1;
        *(uint4*)(sAl + lA0) = rAl0;
        *(uint4*)(sAl + lA1) = rAl1;
        *(uint4*)(sBh + lA0) = rBh;
        *(uint4*)(sBl + lA0) = rBl;
        __syncthreads();
        if (kt + 1 < KT) { LOADT((size_t)(kt + 1) * 32) }   // prefetch next tile

        bf16x8 fah[4], fal[4], fbh[2], fbl[2];
#pragma unroll
        for (int fm = 0; fm < 4; ++fm) {
            fah[fm] = *(const bf16x8*)(sAh + aoff[fm]);
            fal[fm] = *(const bf16x8*)(sAl + aoff[fm]);
        }
#pragma unroll
        for (int fn = 0; fn < 2; ++fn) {
            fbh[fn] = *(const bf16x8*)(sBh + boff[fn]);
            fbl[fn] = *(const bf16x8*)(sBl + boff[fn]);
        }
#pragma unroll
        for (int fm = 0; fm < 4; ++fm)
#pragma unroll
            for (int fn = 0; fn < 2; ++fn) {
                acc[fm][fn] = __builtin_amdgcn_mfma_f32_16x16x32_bf16(fah[fm], fbh[fn], acc[fm][fn], 0, 0, 0);
                acc[fm][fn] = __builtin_amdgcn_mfma_f32_16x16x32_bf16(fah[fm], fbl[fn], acc[fm][fn], 0, 0, 0);
                acc[fm][fn] = __builtin_amdgcn_mfma_f32_16x16x32_bf16(fal[fm], fbh[fn], acc[fm][fn], 0, 0, 0);
            }
    }
#undef LOADT

    // epilogue: D[(lg*4+reg)][lr] per 16x16 fragment
#pragma unroll
    for (int fn = 0; fn < 2; ++fn) {
        int col = bn0 + wn * 32 + fn * 16 + lr;
        float bv = (col < Nc) ? bias[col] : 0.f;
#pragma unroll
        for (int fm = 0; fm < 4; ++fm) {
#pragma unroll
            for (int r = 0; r < 4; ++r) {
                int row = bm0 + wm * 64 + fm * 16 + lg * 4 + r;
                float v = acc[fm][fn][r] + bv;
                if (RELU) v = fmaxf(v, 0.f);
                if (WRITE_BF16) {
                    if (row < M && col < NcPad) {
                        float vv = (col < Nc) ? v : 0.f;
                        u16 hh, ll; split_bf16(vv, hh, ll);
                        Ch[(size_t)row * NcPad + col] = hh;
                        Cl[(size_t)row * NcPad + col] = ll;
                    }
                } else {
                    if (row < M && col < Nc) Cf[(size_t)row * Nc + col] = v;
                }
            }
        }
    }
}

// ---------------- fp32 tiled GEMM (tail, small M) ----------------------------

#define BM 128
#define BNT 64
#define BK 8

__global__ __launch_bounds__(256) void gemm_kernel(const float* __restrict__ A,
                                                   const float* __restrict__ W,
                                                   const float* __restrict__ bias,
                                                   float* __restrict__ C,
                                                   int M, int K, int Nc, int relu) {
    __shared__ float As[BK][BM];
    __shared__ float Bs[BK][BNT];
    int tid = threadIdx.x;
    int bm = blockIdx.x * BM;
    int bn = blockIdx.y * BNT;
    int tx = tid & 15, ty = tid >> 4;

    float acc[8][4];
#pragma unroll
    for (int i = 0; i < 8; ++i)
#pragma unroll
        for (int j = 0; j < 4; ++j) acc[i][j] = 0.f;

    int ar = tid >> 1;
    int ak = (tid & 1) << 2;
    int bk = tid >> 5;
    int bcol = (tid & 31) << 1;

    for (int k0 = 0; k0 < K; k0 += BK) {
        float4 av = {0.f, 0.f, 0.f, 0.f};
        int row = bm + ar;
        if (row < M) av = *(const float4*)(A + (size_t)row * K + k0 + ak);
        As[ak + 0][ar] = av.x; As[ak + 1][ar] = av.y;
        As[ak + 2][ar] = av.z; As[ak + 3][ar] = av.w;
        float2 bv = {0.f, 0.f};
        int col = bn + bcol;
        if (col < Nc) bv = *(const float2*)(W + (size_t)(k0 + bk) * Nc + col);
        Bs[bk][bcol] = bv.x; Bs[bk][bcol + 1] = bv.y;
        __syncthreads();
#pragma unroll
        for (int kk = 0; kk < BK; ++kk) {
            float a[8], b[4];
            *(float4*)(a)     = *(const float4*)(&As[kk][ty * 8]);
            *(float4*)(a + 4) = *(const float4*)(&As[kk][ty * 8 + 4]);
            *(float4*)(b)     = *(const float4*)(&Bs[kk][tx * 4]);
#pragma unroll
            for (int i = 0; i < 8; ++i)
#pragma unroll
                for (int j = 0; j < 4; ++j) acc[i][j] = fmaf(a[i], b[j], acc[i][j]);
        }
        __syncthreads();
    }

#pragma unroll
    for (int i = 0; i < 8; ++i) {
        int row = bm + ty * 8 + i;
        if (row < M) {
            int col = bn + tx * 4;
            if (col < Nc) {
                float4 bb = *(const float4*)(bias + col);
                float4 v;
                v.x = acc[i][0] + bb.x; v.y = acc[i][1] + bb.y;
                v.z = acc[i][2] + bb.z; v.w = acc[i][3] + bb.w;
                if (relu) {
                    v.x = fmaxf(v.x, 0.f); v.y = fmaxf(v.y, 0.f);
                    v.z = fmaxf(v.z, 0.f); v.w = fmaxf(v.w, 0.f);
                }
                *(float4*)(C + (size_t)row * Nc + col) = v;
            }
        }
    }
}

// ---------------- BatchNorm ---------------------------------------------------

#define BN_ROWS 250

__global__ void bn_stats_kernel(const float* __restrict__ h2, float* __restrict__ stats) {
    int c = threadIdx.x;
    if (c >= D) return;
    int r0 = blockIdx.x * BN_ROWS;
    float s = 0.f, q = 0.f;
    for (int r = r0; r < r0 + BN_ROWS; ++r) {
        float v = h2[(size_t)r * D + c];
        s += v; q += v * v;
    }
    atomicAdd(&stats[c], s);
    atomicAdd(&stats[D + c], q);
}

__global__ void bn_norm_kernel(const float* __restrict__ h2, float* __restrict__ hout,
                               const float* __restrict__ stats, const float* __restrict__ gamma,
                               const float* __restrict__ beta, int relu) {
    int idx = blockIdx.x * 256 + threadIdx.x;
    if (idx >= N_NODES * 50) return;
    int node = idx / 50;
    int c = (idx % 50) * 4;
    const float inv = 1.0f / (float)N_NODES;
    float4 v  = *(const float4*)(h2 + (size_t)node * D + c);
    float4 sm = *(const float4*)(stats + c);
    float4 sq = *(const float4*)(stats + D + c);
    float4 gm = *(const float4*)(gamma + c);
    float4 bt = *(const float4*)(beta + c);
    float m, var, sc, o;
    m = sm.x * inv; var = sq.x * inv - m * m; sc = gm.x / sqrtf(var + EPS);
    o = (v.x - m) * sc + bt.x; v.x = relu ? fmaxf(o, 0.f) : o;
    m = sm.y * inv; var = sq.y * inv - m * m; sc = gm.y / sqrtf(var + EPS);
    o = (v.y - m) * sc + bt.y; v.y = relu ? fmaxf(o, 0.f) : o;
    m = sm.z * inv; var = sq.z * inv - m * m; sc = gm.z / sqrtf(var + EPS);
    o = (v.z - m) * sc + bt.z; v.z = relu ? fmaxf(o, 0.f) : o;
    m = sm.w * inv; var = sq.w * inv - m * m; sc = gm.w / sqrtf(var + EPS);
    o = (v.w - m) * sc + bt.w; v.w = relu ? fmaxf(o, 0.f) : o;
    *(float4*)(hout + (size_t)node * D + c) = v;
}

// ---------------- global mean pool --------------------------------------------

__global__ void pool_kernel(const float* __restrict__ h, const int* __restrict__ gstart,
                            float* __restrict__ hg) {
    int idx = blockIdx.x * 256 + threadIdx.x;
    if (idx >= NGRAPH * 50) return;
    int g = idx / 50;
    int c = (idx % 50) * 4;
    int s = gstart[g], e = gstart[g + 1];
    float4 acc = {0.f, 0.f, 0.f, 0.f};
    for (int r = s; r < e; ++r) {
        float4 v = *(const float4*)(h + (size_t)r * D + c);
        acc.x += v.x; acc.y += v.y; acc.z += v.z; acc.w += v.w;
    }
    float inv = 1.0f / fmaxf((float)(e - s), 1.0f);
    acc.x *= inv; acc.y *= inv; acc.z *= inv; acc.w *= inv;
    *(float4*)(hg + (size_t)g * D + c) = acc;
}

// ---------------- launch -------------------------------------------------------

extern "C" void kernel_launch(void* const* d_in, const int* in_sizes, int n_in,
                              void* d_out, int out_size, void* d_ws, size_t ws_size,
                              hipStream_t stream) {
    const int*   x       = (const int*)d_in[0];
    const int*   ei      = (const int*)d_in[1];
    const int*   ea      = (const int*)d_in[2];
    const int*   batch   = (const int*)d_in[3];
    const float* x_emb1  = (const float*)d_in[4];
    const float* x_emb2  = (const float*)d_in[5];
    const float* e1w     = (const float*)d_in[6];
    const float* e2w     = (const float*)d_in[7];
    const float* w1      = (const float*)d_in[8];
    const float* b1      = (const float*)d_in[9];
    const float* w2      = (const float*)d_in[10];
    const float* b2      = (const float*)d_in[11];
    const float* gamma   = (const float*)d_in[12];
    const float* beta    = (const float*)d_in[13];
    const float* feat_w  = (const float*)d_in[14];
    const float* feat_b  = (const float*)d_in[15];
    const float* out_w1  = (const float*)d_in[16];
    const float* out_b1  = (const float*)d_in[17];
    const float* out_w2  = (const float*)d_in[18];
    const float* out_b2  = (const float*)d_in[19];
    const int* src = ei;
    const int* dst = ei + N_EDGES;

    char* p = (char*)d_ws;
    auto alloc = [&](size_t bytes) -> void* {
        void* r = (void*)p;
        p += (bytes + 255) & ~(size_t)255;
        return r;
    };
    const int MPAD = 50048;                         // 391*128
    float* h      = (float*)alloc((size_t)N_NODES * D * 4);          // 40 MB
    u16*   aggrAh = (u16*)alloc((size_t)MPAD * 224 * 2);             // 22.4 MB  } region R
    u16*   aggrAl = (u16*)alloc((size_t)MPAD * 224 * 2);             // 22.4 MB  }
    float* aggr   = (float*)aggrAh;  // fp32 [50000][200] aliased over R (40MB <= 44.8MB)
    u16*   h1h    = (u16*)alloc((size_t)MPAD * 416 * 2);             // 41.6 MB
    u16*   h1l    = (u16*)alloc((size_t)MPAD * 416 * 2);             // 41.6 MB
    u16*   wt1h   = (u16*)alloc((size_t)NLAYERS * 448 * 224 * 2);    // 2.0 MB
    u16*   wt1l   = (u16*)alloc((size_t)NLAYERS * 448 * 224 * 2);
    u16*   wt2h   = (u16*)alloc((size_t)NLAYERS * 256 * 416 * 2);    // 2.1 MB
    u16*   wt2l   = (u16*)alloc((size_t)NLAYERS * 256 * 416 * 2);
    int*   counts    = (int*)alloc(N_NODES * 4);
    int*   row_start = (int*)alloc((N_NODES + 1) * 4);
    int*   cursor    = (int*)alloc(N_NODES * 4);
    int*   edge_list = (int*)alloc(N_EDGES * 4);
    int*   psum      = (int*)alloc(256 * 4);
    int*   poff      = (int*)alloc(256 * 4);
    int*   gstart    = (int*)alloc((NGRAPH + 1) * 4);
    float* stats     = (float*)alloc(2 * D * 4);
    float* hg        = (float*)alloc((size_t)NGRAPH * D * 4);
    float* tbuf      = (float*)alloc((size_t)NGRAPH * D * 4);
    float* outf      = (float*)d_out;

    const int NCHUNK = (N_NODES + 255) / 256;

    // weight prep (once per launch)
    prep_w1_kernel<<<(NLAYERS * 448 * 224 + 255) / 256, 256, 0, stream>>>(w1, wt1h, wt1l);
    prep_w2_kernel<<<(NLAYERS * 256 * 416 + 255) / 256, 256, 0, stream>>>(w2, wt2h, wt2l);

    // CSR build + graph bounds
    hipMemsetAsync(counts, 0, N_NODES * 4, stream);
    count_kernel<<<(N_EDGES + 255) / 256, 256, 0, stream>>>(dst, counts);
    scan1_kernel<<<NCHUNK, 256, 0, stream>>>(counts, psum);
    scan2_kernel<<<1, 256, 0, stream>>>(psum, poff, NCHUNK);
    scan3_kernel<<<NCHUNK, 256, 0, stream>>>(counts, poff, row_start, cursor);
    scatter_kernel<<<(N_EDGES + 255) / 256, 256, 0, stream>>>(dst, cursor, edge_list);
    bounds_kernel<<<(NGRAPH + 1 + 255) / 256, 256, 0, stream>>>(batch, gstart);

    embed_kernel<<<(N_NODES * 50 + 255) / 256, 256, 0, stream>>>(x, x_emb1, x_emb2, h);

    dim3 g1(391, 7);   // GEMM1: M=50000(pad 50048), N=400(pad 416), K=224
    dim3 g2(391, 4);   // GEMM2: M=50000, N=200, K=416
    for (int l = 0; l < NLAYERS; ++l) {
        aggregate_kernel<<<(N_NODES * 56 + 255) / 256, 256, 0, stream>>>(
            h, e1w + (size_t)l * 5 * D, e2w + (size_t)l * 3 * D,
            row_start, edge_list, src, ea, aggrAh, aggrAl);
        gemm_mfma<1, 1><<<g1, 256, 0, stream>>>(
            aggrAh, aggrAl, wt1h + (size_t)l * 448 * 224, wt1l + (size_t)l * 448 * 224,
            b1 + (size_t)l * 400, nullptr, h1h, h1l, N_NODES, 224, 400, 416, 7);
        gemm_mfma<0, 0><<<g2, 256, 0, stream>>>(
            h1h, h1l, wt2h + (size_t)l * 256 * 416, wt2l + (size_t)l * 256 * 416,
            b2 + (size_t)l * 200, aggr, nullptr, nullptr, N_NODES, 416, 200, 200, 13);
        hipMemsetAsync(stats, 0, 2 * D * 4, stream);
        bn_stats_kernel<<<200, 256, 0, stream>>>(aggr, stats);
        bn_norm_kernel<<<(N_NODES * 50 + 255) / 256, 256, 0, stream>>>(
            aggr, h, stats, gamma + (size_t)l * D, beta + (size_t)l * D,
            (l < NLAYERS - 1) ? 1 : 0);
    }

    pool_kernel<<<(NGRAPH * 50 + 255) / 256, 256, 0, stream>>>(h, gstart, hg);

    dim3 gp((NGRAPH + BM - 1) / BM, (D + BNT - 1) / BNT);
    gemm_kernel<<<gp, 256, 0, stream>>>(hg, feat_w, feat_b, outf, NGRAPH, D, D, 0);
    gemm_kernel<<<gp, 256, 0, stream>>>(outf, out_w1, out_b1, tbuf, NGRAPH, D, D, 1);
    dim3 go((NGRAPH + BM - 1) / BM, (100 + BNT - 1) / BNT);
    gemm_kernel<<<go, 256, 0, stream>>>(tbuf, out_w2, out_b2, outf + (size_t)NGRAPH * D,
                                        NGRAPH, D, 100, 0);
    hipMemcpyAsync(outf + (size_t)NGRAPH * D + (size_t)NGRAPH * 100,
                   outf + (size_t)NGRAPH * D,
                   (size_t)NGRAPH * 100 * 4, hipMemcpyDeviceToDevice, stream);
}

// Round 3
// 2480.805 us; speedup vs baseline: 1.5726x; 1.1074x over previous
//
#include <hip/hip_runtime.h>

#define N_NODES 50000
#define N_EDGES 200000
#define D 200
#define NLAYERS 10
#define NGRAPH 2500
#define EPS 1e-5f

typedef unsigned short u16;
typedef __attribute__((ext_vector_type(8))) __bf16 bf16x8;
typedef __attribute__((ext_vector_type(4))) float f32x4;

// fp32 -> bf16 RNE
__device__ __forceinline__ u16 f2bf_rne(float x) {
    union { float f; unsigned u; } c; c.f = x;
    unsigned r = c.u + 0x7FFF + ((c.u >> 16) & 1);
    return (u16)(r >> 16);
}
__device__ __forceinline__ void split_bf16(float x, u16& h, u16& l) {
    h = f2bf_rne(x);
    union { unsigned u; float f; } c; c.u = ((unsigned)h) << 16;
    l = f2bf_rne(x - c.f);
}

// ---------------- CSR build -------------------------------------------------

__global__ void count_kernel(const int* __restrict__ dst, int* __restrict__ counts) {
    int e = blockIdx.x * 256 + threadIdx.x;
    if (e < N_EDGES) atomicAdd(&counts[dst[e]], 1);
}

__global__ void scan1_kernel(const int* __restrict__ counts, int* __restrict__ psum) {
    __shared__ int s[256];
    int idx = blockIdx.x * 256 + threadIdx.x;
    s[threadIdx.x] = (idx < N_NODES) ? counts[idx] : 0;
    __syncthreads();
    for (int off = 128; off > 0; off >>= 1) {
        if (threadIdx.x < off) s[threadIdx.x] += s[threadIdx.x + off];
        __syncthreads();
    }
    if (threadIdx.x == 0) psum[blockIdx.x] = s[0];
}

__global__ void scan2_kernel(const int* __restrict__ psum, int* __restrict__ poff, int nchunk) {
    __shared__ int s[256];
    int t = threadIdx.x;
    int v = (t < nchunk) ? psum[t] : 0;
    s[t] = v;
    __syncthreads();
    for (int off = 1; off < 256; off <<= 1) {
        int xv = (t >= off) ? s[t - off] : 0;
        __syncthreads();
        s[t] += xv;
        __syncthreads();
    }
    if (t < nchunk) poff[t] = s[t] - v;
}

__global__ void scan3_kernel(const int* __restrict__ counts, const int* __restrict__ poff,
                             int* __restrict__ row_start, int* __restrict__ cursor) {
    __shared__ int s[256];
    int t = threadIdx.x;
    int idx = blockIdx.x * 256 + t;
    int v = (idx < N_NODES) ? counts[idx] : 0;
    s[t] = v;
    __syncthreads();
    for (int off = 1; off < 256; off <<= 1) {
        int xv = (t >= off) ? s[t - off] : 0;
        __syncthreads();
        s[t] += xv;
        __syncthreads();
    }
    if (idx < N_NODES) {
        int rs = poff[blockIdx.x] + s[t] - v;
        row_start[idx] = rs;
        cursor[idx] = rs;
    }
    if (blockIdx.x == 0 && t == 0) row_start[N_NODES] = N_EDGES;
}

__global__ void scatter_kernel(const int* __restrict__ dst, int* __restrict__ cursor,
                               int* __restrict__ edge_list) {
    int e = blockIdx.x * 256 + threadIdx.x;
    if (e < N_EDGES) {
        int p = atomicAdd(&cursor[dst[e]], 1);
        edge_list[p] = e;
    }
}

__global__ void bounds_kernel(const int* __restrict__ batch, int* __restrict__ gstart) {
    int g = blockIdx.x * 256 + threadIdx.x;
    if (g > NGRAPH) return;
    if (g == NGRAPH) { gstart[NGRAPH] = N_NODES; return; }
    int lo = 0, hi = N_NODES;
    while (lo < hi) { int mid = (lo + hi) >> 1; if (batch[mid] < g) lo = mid + 1; else hi = mid; }
    gstart[g] = lo;
}

// ---------------- weight prep: transpose + pad + bf16 hi/lo split ------------
// Wt1: [L][512][224]  (row = output col n of W1, col = k)
// Wt2: [L][256][416]

__global__ void prep_w1_kernel(const float* __restrict__ w, u16* __restrict__ wh, u16* __restrict__ wl) {
    int idx = blockIdx.x * 256 + threadIdx.x;
    if (idx >= NLAYERS * 512 * 224) return;
    int k = idx % 224;
    int n = (idx / 224) % 512;
    int l = idx / (224 * 512);
    float v = (k < 200 && n < 400) ? w[((size_t)l * 200 + k) * 400 + n] : 0.f;
    u16 hh, ll; split_bf16(v, hh, ll);
    wh[idx] = hh; wl[idx] = ll;
}

__global__ void prep_w2_kernel(const float* __restrict__ w, u16* __restrict__ wh, u16* __restrict__ wl) {
    int idx = blockIdx.x * 256 + threadIdx.x;
    if (idx >= NLAYERS * 256 * 416) return;
    int k = idx % 416;
    int n = (idx / 416) % 256;
    int l = idx / (416 * 256);
    float v = (k < 400 && n < 200) ? w[((size_t)l * 400 + k) * 200 + n] : 0.f;
    u16 hh, ll; split_bf16(v, hh, ll);
    wh[idx] = hh; wl[idx] = ll;
}

// ---------------- node feature init ------------------------------------------

__global__ void embed_kernel(const int* __restrict__ x, const float* __restrict__ emb1,
                             const float* __restrict__ emb2, float* __restrict__ h) {
    int idx = blockIdx.x * 256 + threadIdx.x;
    if (idx >= N_NODES * 50) return;
    int node = idx / 50;
    int c = (idx % 50) * 4;
    int a = x[node * 2], b = x[node * 2 + 1];
    float4 v1 = *(const float4*)(emb1 + (size_t)a * D + c);
    float4 v2 = *(const float4*)(emb2 + (size_t)b * D + c);
    float4 o;
    o.x = v1.x + v2.x; o.y = v1.y + v2.y; o.z = v1.z + v2.z; o.w = v1.w + v2.w;
    *(float4*)(h + (size_t)node * D + c) = o;
}

// ---------------- message + aggregate (+fused BN-norm+ReLU of prev layer) ----
// HAS_BN=0: input is plain h (layer 0). HAS_BN=1: input is raw GEMM2 output,
// normalized on the fly with (v*a + b), then ReLU (prev layer is always <L-1).

template <int HAS_BN>
__global__ void aggregate_kernel(const float* __restrict__ hin,
                                 const float* __restrict__ stats,
                                 const float* __restrict__ gamma, const float* __restrict__ beta,
                                 const float* __restrict__ e1, const float* __restrict__ e2,
                                 const int* __restrict__ row_start, const int* __restrict__ edge_list,
                                 const int* __restrict__ src, const int* __restrict__ edge_attr,
                                 u16* __restrict__ Ah, u16* __restrict__ Al) {
    __shared__ float t1[5 * D];
    __shared__ float t2[3 * D];
    for (int i = threadIdx.x; i < 5 * D; i += 256) t1[i] = e1[i];
    for (int i = threadIdx.x; i < 3 * D; i += 256) t2[i] = e2[i];
    __syncthreads();
    int idx = blockIdx.x * 256 + threadIdx.x;
    if (idx >= N_NODES * 56) return;
    int node = idx / 56;
    int c = (idx % 56) * 4;
    size_t ob = (size_t)node * 224 + c;
    if (c >= 200) {  // K padding
        *(uint2*)(Ah + ob) = make_uint2(0u, 0u);
        *(uint2*)(Al + ob) = make_uint2(0u, 0u);
        return;
    }
    float a[4], b[4];
    if (HAS_BN) {
        const float invN = 1.0f / (float)N_NODES;
#pragma unroll
        for (int j = 0; j < 4; ++j) {
            float s = stats[c + j], q = stats[256 + c + j];
            float m = s * invN;
            float var = q * invN - m * m;
            float sc = gamma[c + j] * rsqrtf(var + EPS);
            a[j] = sc; b[j] = beta[c + j] - m * sc;
        }
    }
    float4 acc = *(const float4*)(hin + (size_t)node * D + c);
    if (HAS_BN) {
        acc.x = fmaxf(acc.x * a[0] + b[0], 0.f);
        acc.y = fmaxf(acc.y * a[1] + b[1], 0.f);
        acc.z = fmaxf(acc.z * a[2] + b[2], 0.f);
        acc.w = fmaxf(acc.w * a[3] + b[3], 0.f);
    }
    acc.x += t1[4 * D + c + 0] + t2[c + 0];
    acc.y += t1[4 * D + c + 1] + t2[c + 1];
    acc.z += t1[4 * D + c + 2] + t2[c + 2];
    acc.w += t1[4 * D + c + 3] + t2[c + 3];
    int jb = row_start[node], je = row_start[node + 1];
    for (int j = jb; j < je; ++j) {
        int e = edge_list[j];
        int s = src[e];
        int2 eav = *(const int2*)(edge_attr + 2 * e);
        float4 hv = *(const float4*)(hin + (size_t)s * D + c);
        if (HAS_BN) {
            hv.x = fmaxf(hv.x * a[0] + b[0], 0.f);
            hv.y = fmaxf(hv.y * a[1] + b[1], 0.f);
            hv.z = fmaxf(hv.z * a[2] + b[2], 0.f);
            hv.w = fmaxf(hv.w * a[3] + b[3], 0.f);
        }
        const float* p1 = t1 + eav.x * D + c;
        const float* p2 = t2 + eav.y * D + c;
        acc.x += hv.x + p1[0] + p2[0];
        acc.y += hv.y + p1[1] + p2[1];
        acc.z += hv.z + p1[2] + p2[2];
        acc.w += hv.w + p1[3] + p2[3];
    }
    u16 h0, l0, h1v, l1, h2v, l2, h3v, l3;
    split_bf16(acc.x, h0, l0); split_bf16(acc.y, h1v, l1);
    split_bf16(acc.z, h2v, l2); split_bf16(acc.w, h3v, l3);
    ushort4 vh; vh.x = h0; vh.y = h1v; vh.z = h2v; vh.w = h3v;
    ushort4 vl; vl.x = l0; vl.y = l1; vl.z = l2; vl.w = l3;
    *(ushort4*)(Ah + ob) = vh;
    *(ushort4*)(Al + ob) = vl;
}

// ---------------- bf16x2 MFMA GEMM, 128x128 tile ------------------------------
// C[M,Nc] = A[M,Kpad] @ Wt[Nc',Kpad]^T + bias. 3-term hi/lo bf16.
// 4 waves (2x2), wave tile 64x64, K-step 32, 16x16x32 MFMA.
// grid: x = N-blocks (fast -> row-band L2 reuse), y = M-blocks.
// LDS swizzle: elem offset(row, g) = row*32 + (g ^ ((row>>1)&3))*8  (0 conflicts, r2-verified)

template <int RELU, int WRITE_BF16, int STATS>
__global__ __launch_bounds__(256) void gemm_mfma(
    const u16* __restrict__ Ah, const u16* __restrict__ Al,
    const u16* __restrict__ Bh, const u16* __restrict__ Bl,
    const float* __restrict__ bias,
    float* __restrict__ Cf, u16* __restrict__ Ch, u16* __restrict__ Cl,
    float* __restrict__ stats,
    int M, int Kpad, int Nc, int NcPad, int KT)
{
    __shared__ alignas(16) u16 sAh[128 * 32];
    __shared__ alignas(16) u16 sAl[128 * 32];
    __shared__ alignas(16) u16 sBh[128 * 32];
    __shared__ alignas(16) u16 sBl[128 * 32];

    const int tid = threadIdx.x;
    const int lane = tid & 63;
    const int wid = tid >> 6;
    const int wm = wid >> 1, wn = wid & 1;
    const int lr = lane & 15, lg = lane >> 4;
    const int bm0 = blockIdx.y * 128;
    const int bn0 = blockIdx.x * 128;

    const int r0 = tid >> 2;
    const int gd = tid & 3;
    const int slot = gd ^ ((r0 >> 1) & 3);
    const int lO0 = r0 * 32 + slot * 8;
    const int lO1 = lO0 + 64 * 32;
    const size_t gA0 = (size_t)(bm0 + r0) * Kpad + gd * 8;
    const size_t gA1 = gA0 + (size_t)64 * Kpad;
    const size_t gB0 = (size_t)(bn0 + r0) * Kpad + gd * 8;
    const size_t gB1 = gB0 + (size_t)64 * Kpad;

    f32x4 acc[4][4];
#pragma unroll
    for (int i = 0; i < 4; ++i)
#pragma unroll
        for (int j = 0; j < 4; ++j) acc[i][j] = (f32x4){0.f, 0.f, 0.f, 0.f};

    int aoff[4], boff[4];
#pragma unroll
    for (int f = 0; f < 4; ++f) {
        int arow = wm * 64 + f * 16 + lr;
        aoff[f] = arow * 32 + ((lg ^ ((arow >> 1) & 3)) * 8);
        int brow = wn * 64 + f * 16 + lr;
        boff[f] = brow * 32 + ((lg ^ ((brow >> 1) & 3)) * 8);
    }

    uint4 rAh0, rAh1, rAl0, rAl1, rBh0, rBh1, rBl0, rBl1;
#define LOADT(K0)                                          \
    rAh0 = *(const uint4*)(Ah + gA0 + (K0));               \
    rAh1 = *(const uint4*)(Ah + gA1 + (K0));               \
    rAl0 = *(const uint4*)(Al + gA0 + (K0));               \
    rAl1 = *(const uint4*)(Al + gA1 + (K0));               \
    rBh0 = *(const uint4*)(Bh + gB0 + (K0));               \
    rBh1 = *(const uint4*)(Bh + gB1 + (K0));               \
    rBl0 = *(const uint4*)(Bl + gB0 + (K0));               \
    rBl1 = *(const uint4*)(Bl + gB1 + (K0));

    LOADT(0)
    for (int kt = 0; kt < KT; ++kt) {
        if (kt > 0) __syncthreads();
        *(uint4*)(sAh + lO0) = rAh0;
        *(uint4*)(sAh + lO1) = rAh1;
        *(uint4*)(sAl + lO0) = rAl0;
        *(uint4*)(sAl + lO1) = rAl1;
        *(uint4*)(sBh + lO0) = rBh0;
        *(uint4*)(sBh + lO1) = rBh1;
        *(uint4*)(sBl + lO0) = rBl0;
        *(uint4*)(sBl + lO1) = rBl1;
        __syncthreads();
        if (kt + 1 < KT) { LOADT((size_t)(kt + 1) * 32) }

        bf16x8 fbh[4], fbl[4];
#pragma unroll
        for (int fn = 0; fn < 4; ++fn) {
            fbh[fn] = *(const bf16x8*)(sBh + boff[fn]);
            fbl[fn] = *(const bf16x8*)(sBl + boff[fn]);
        }
#pragma unroll
        for (int fm = 0; fm < 4; ++fm) {
            bf16x8 fah = *(const bf16x8*)(sAh + aoff[fm]);
            bf16x8 fal = *(const bf16x8*)(sAl + aoff[fm]);
#pragma unroll
            for (int fn = 0; fn < 4; ++fn) {
                acc[fm][fn] = __builtin_amdgcn_mfma_f32_16x16x32_bf16(fah, fbh[fn], acc[fm][fn], 0, 0, 0);
                acc[fm][fn] = __builtin_amdgcn_mfma_f32_16x16x32_bf16(fah, fbl[fn], acc[fm][fn], 0, 0, 0);
                acc[fm][fn] = __builtin_amdgcn_mfma_f32_16x16x32_bf16(fal, fbh[fn], acc[fm][fn], 0, 0, 0);
            }
        }
    }
#undef LOADT

    // epilogue: frag D row = lg*4+r, col = lr
#pragma unroll
    for (int fn = 0; fn < 4; ++fn) {
        int col = bn0 + wn * 64 + fn * 16 + lr;
        float bv = (col < Nc) ? bias[col] : 0.f;
        if (WRITE_BF16) {
            if (col < NcPad) {
#pragma unroll
                for (int fm = 0; fm < 4; ++fm) {
#pragma unroll
                    for (int r = 0; r < 4; ++r) {
                        int row = bm0 + wm * 64 + fm * 16 + lg * 4 + r;
                        if (row < M) {
                            float v = acc[fm][fn][r] + bv;
                            if (RELU) v = fmaxf(v, 0.f);
                            if (col >= Nc) v = 0.f;   // h1 K-padding cols must be 0
                            u16 hh, ll; split_bf16(v, hh, ll);
                            Ch[(size_t)row * NcPad + col] = hh;
                            Cl[(size_t)row * NcPad + col] = ll;
                        }
                    }
                }
            }
        } else {
            float s = 0.f, q = 0.f;
#pragma unroll
            for (int fm = 0; fm < 4; ++fm) {
#pragma unroll
                for (int r = 0; r < 4; ++r) {
                    int row = bm0 + wm * 64 + fm * 16 + lg * 4 + r;
                    if (row < M && col < Nc) {
                        float v = acc[fm][fn][r] + bv;
                        if (RELU) v = fmaxf(v, 0.f);
                        Cf[(size_t)row * Nc + col] = v;
                        if (STATS) { s += v; q += v * v; }
                    }
                }
            }
            if (STATS) {
                s += __shfl_xor(s, 16); s += __shfl_xor(s, 32);
                q += __shfl_xor(q, 16); q += __shfl_xor(q, 32);
                if (lg == 0 && col < Nc) {
                    atomicAdd(&stats[col], s);
                    atomicAdd(&stats[256 + col], q);
                }
            }
        }
    }
}

// ---------------- fp32 tiled GEMM (tail, small M) ----------------------------

#define BM 128
#define BNT 64
#define BK 8

__global__ __launch_bounds__(256) void gemm_kernel(const float* __restrict__ A,
                                                   const float* __restrict__ W,
                                                   const float* __restrict__ bias,
                                                   float* __restrict__ C,
                                                   int M, int K, int Nc, int relu) {
    __shared__ float As[BK][BM];
    __shared__ float Bs[BK][BNT];
    int tid = threadIdx.x;
    int bm = blockIdx.x * BM;
    int bn = blockIdx.y * BNT;
    int tx = tid & 15, ty = tid >> 4;

    float acc[8][4];
#pragma unroll
    for (int i = 0; i < 8; ++i)
#pragma unroll
        for (int j = 0; j < 4; ++j) acc[i][j] = 0.f;

    int ar = tid >> 1;
    int ak = (tid & 1) << 2;
    int bk = tid >> 5;
    int bcol = (tid & 31) << 1;

    for (int k0 = 0; k0 < K; k0 += BK) {
        float4 av = {0.f, 0.f, 0.f, 0.f};
        int row = bm + ar;
        if (row < M) av = *(const float4*)(A + (size_t)row * K + k0 + ak);
        As[ak + 0][ar] = av.x; As[ak + 1][ar] = av.y;
        As[ak + 2][ar] = av.z; As[ak + 3][ar] = av.w;
        float2 bv = {0.f, 0.f};
        int col = bn + bcol;
        if (col < Nc) bv = *(const float2*)(W + (size_t)(k0 + bk) * Nc + col);
        Bs[bk][bcol] = bv.x; Bs[bk][bcol + 1] = bv.y;
        __syncthreads();
#pragma unroll
        for (int kk = 0; kk < BK; ++kk) {
            float a[8], b[4];
            *(float4*)(a)     = *(const float4*)(&As[kk][ty * 8]);
            *(float4*)(a + 4) = *(const float4*)(&As[kk][ty * 8 + 4]);
            *(float4*)(b)     = *(const float4*)(&Bs[kk][tx * 4]);
#pragma unroll
            for (int i = 0; i < 8; ++i)
#pragma unroll
                for (int j = 0; j < 4; ++j) acc[i][j] = fmaf(a[i], b[j], acc[i][j]);
        }
        __syncthreads();
    }

#pragma unroll
    for (int i = 0; i < 8; ++i) {
        int row = bm + ty * 8 + i;
        if (row < M) {
            int col = bn + tx * 4;
            if (col < Nc) {
                float4 bb = *(const float4*)(bias + col);
                float4 v;
                v.x = acc[i][0] + bb.x; v.y = acc[i][1] + bb.y;
                v.z = acc[i][2] + bb.z; v.w = acc[i][3] + bb.w;
                if (relu) {
                    v.x = fmaxf(v.x, 0.f); v.y = fmaxf(v.y, 0.f);
                    v.z = fmaxf(v.z, 0.f); v.w = fmaxf(v.w, 0.f);
                }
                *(float4*)(C + (size_t)row * Nc + col) = v;
            }
        }
    }
}

// ---------------- global mean pool (+fused BN of last layer, no relu) --------

__global__ void pool_bn_kernel(const float* __restrict__ g2, const float* __restrict__ stats,
                               const float* __restrict__ gamma, const float* __restrict__ beta,
                               const int* __restrict__ gstart, float* __restrict__ hg) {
    int idx = blockIdx.x * 256 + threadIdx.x;
    if (idx >= NGRAPH * 50) return;
    int g = idx / 50;
    int c = (idx % 50) * 4;
    float a[4], b[4];
    const float invN = 1.0f / (float)N_NODES;
#pragma unroll
    for (int j = 0; j < 4; ++j) {
        float s = stats[c + j], q = stats[256 + c + j];
        float m = s * invN;
        float var = q * invN - m * m;
        float sc = gamma[c + j] * rsqrtf(var + EPS);
        a[j] = sc; b[j] = beta[c + j] - m * sc;
    }
    int s0 = gstart[g], e0 = gstart[g + 1];
    float4 acc = {0.f, 0.f, 0.f, 0.f};
    for (int r = s0; r < e0; ++r) {
        float4 v = *(const float4*)(g2 + (size_t)r * D + c);
        acc.x += v.x; acc.y += v.y; acc.z += v.z; acc.w += v.w;
    }
    float inv = 1.0f / fmaxf((float)(e0 - s0), 1.0f);
    // affine commutes with mean (exact in math; rounding negligible)
    acc.x = acc.x * inv * a[0] + b[0];
    acc.y = acc.y * inv * a[1] + b[1];
    acc.z = acc.z * inv * a[2] + b[2];
    acc.w = acc.w * inv * a[3] + b[3];
    *(float4*)(hg + (size_t)g * D + c) = acc;
}

// ---------------- launch -------------------------------------------------------

extern "C" void kernel_launch(void* const* d_in, const int* in_sizes, int n_in,
                              void* d_out, int out_size, void* d_ws, size_t ws_size,
                              hipStream_t stream) {
    const int*   x       = (const int*)d_in[0];
    const int*   ei      = (const int*)d_in[1];
    const int*   ea      = (const int*)d_in[2];
    const int*   batch   = (const int*)d_in[3];
    const float* x_emb1  = (const float*)d_in[4];
    const float* x_emb2  = (const float*)d_in[5];
    const float* e1w     = (const float*)d_in[6];
    const float* e2w     = (const float*)d_in[7];
    const float* w1      = (const float*)d_in[8];
    const float* b1      = (const float*)d_in[9];
    const float* w2      = (const float*)d_in[10];
    const float* b2      = (const float*)d_in[11];
    const float* gamma   = (const float*)d_in[12];
    const float* beta    = (const float*)d_in[13];
    const float* feat_w  = (const float*)d_in[14];
    const float* feat_b  = (const float*)d_in[15];
    const float* out_w1  = (const float*)d_in[16];
    const float* out_b1  = (const float*)d_in[17];
    const float* out_w2  = (const float*)d_in[18];
    const float* out_b2  = (const float*)d_in[19];
    const int* src = ei;
    const int* dst = ei + N_EDGES;

    char* p = (char*)d_ws;
    auto alloc = [&](size_t bytes) -> void* {
        void* r = (void*)p;
        p += (bytes + 255) & ~(size_t)255;
        return r;
    };
    const int MPAD = 50048;                         // 391*128
    // h (layer-0 input) and g2 (raw GEMM2 output) share a buffer: embed->aggregate0
    // fully consumes h before layer-0 GEMM2 overwrites it (stream-ordered).
    float* h      = (float*)alloc((size_t)N_NODES * D * 4);          // 40 MB
    float* g2     = h;
    u16*   aggrAh = (u16*)alloc((size_t)MPAD * 224 * 2);             // 22.4 MB
    u16*   aggrAl = (u16*)alloc((size_t)MPAD * 224 * 2);             // 22.4 MB
    u16*   h1h    = (u16*)alloc((size_t)MPAD * 416 * 2);             // 41.6 MB
    u16*   h1l    = (u16*)alloc((size_t)MPAD * 416 * 2);             // 41.6 MB
    u16*   wt1h   = (u16*)alloc((size_t)NLAYERS * 512 * 224 * 2);    // 2.3 MB
    u16*   wt1l   = (u16*)alloc((size_t)NLAYERS * 512 * 224 * 2);
    u16*   wt2h   = (u16*)alloc((size_t)NLAYERS * 256 * 416 * 2);    // 2.1 MB
    u16*   wt2l   = (u16*)alloc((size_t)NLAYERS * 256 * 416 * 2);
    int*   counts    = (int*)alloc(N_NODES * 4);
    int*   row_start = (int*)alloc((N_NODES + 1) * 4);
    int*   cursor    = (int*)alloc(N_NODES * 4);
    int*   edge_list = (int*)alloc(N_EDGES * 4);
    int*   psum      = (int*)alloc(256 * 4);
    int*   poff      = (int*)alloc(256 * 4);
    int*   gstart    = (int*)alloc((NGRAPH + 1) * 4);
    float* stats     = (float*)alloc(512 * 4);       // [sum 256][sumsq 256]
    float* hg        = (float*)alloc((size_t)NGRAPH * D * 4);
    float* tbuf      = (float*)alloc((size_t)NGRAPH * D * 4);
    float* outf      = (float*)d_out;

    const int NCHUNK = (N_NODES + 255) / 256;

    // weight prep (once per launch)
    prep_w1_kernel<<<(NLAYERS * 512 * 224 + 255) / 256, 256, 0, stream>>>(w1, wt1h, wt1l);
    prep_w2_kernel<<<(NLAYERS * 256 * 416 + 255) / 256, 256, 0, stream>>>(w2, wt2h, wt2l);

    // CSR build + graph bounds
    hipMemsetAsync(counts, 0, N_NODES * 4, stream);
    count_kernel<<<(N_EDGES + 255) / 256, 256, 0, stream>>>(dst, counts);
    scan1_kernel<<<NCHUNK, 256, 0, stream>>>(counts, psum);
    scan2_kernel<<<1, 256, 0, stream>>>(psum, poff, NCHUNK);
    scan3_kernel<<<NCHUNK, 256, 0, stream>>>(counts, poff, row_start, cursor);
    scatter_kernel<<<(N_EDGES + 255) / 256, 256, 0, stream>>>(dst, cursor, edge_list);
    bounds_kernel<<<(NGRAPH + 1 + 255) / 256, 256, 0, stream>>>(batch, gstart);

    embed_kernel<<<(N_NODES * 50 + 255) / 256, 256, 0, stream>>>(x, x_emb1, x_emb2, h);

    dim3 g1(4, 391);   // GEMM1: x = N-blocks (512 pad), y = M-blocks
    dim3 g2d(2, 391);  // GEMM2: x = N-blocks (256 pad)
    for (int l = 0; l < NLAYERS; ++l) {
        if (l == 0)
            aggregate_kernel<0><<<(N_NODES * 56 + 255) / 256, 256, 0, stream>>>(
                h, nullptr, nullptr, nullptr,
                e1w, e2w, row_start, edge_list, src, ea, aggrAh, aggrAl);
        else
            aggregate_kernel<1><<<(N_NODES * 56 + 255) / 256, 256, 0, stream>>>(
                g2, stats, gamma + (size_t)(l - 1) * D, beta + (size_t)(l - 1) * D,
                e1w + (size_t)l * 5 * D, e2w + (size_t)l * 3 * D,
                row_start, edge_list, src, ea, aggrAh, aggrAl);
        gemm_mfma<1, 1, 0><<<g1, 256, 0, stream>>>(
            aggrAh, aggrAl, wt1h + (size_t)l * 512 * 224, wt1l + (size_t)l * 512 * 224,
            b1 + (size_t)l * 400, nullptr, h1h, h1l, nullptr, N_NODES, 224, 400, 416, 7);
        hipMemsetAsync(stats, 0, 512 * 4, stream);
        gemm_mfma<0, 0, 1><<<g2d, 256, 0, stream>>>(
            h1h, h1l, wt2h + (size_t)l * 256 * 416, wt2l + (size_t)l * 256 * 416,
            b2 + (size_t)l * 200, g2, nullptr, nullptr, stats, N_NODES, 416, 200, 200, 13);
    }

    pool_bn_kernel<<<(NGRAPH * 50 + 255) / 256, 256, 0, stream>>>(
        g2, stats, gamma + (size_t)(NLAYERS - 1) * D, beta + (size_t)(NLAYERS - 1) * D,
        gstart, hg);

    dim3 gp((NGRAPH + BM - 1) / BM, (D + BNT - 1) / BNT);
    gemm_kernel<<<gp, 256, 0, stream>>>(hg, feat_w, feat_b, outf, NGRAPH, D, D, 0);
    gemm_kernel<<<gp, 256, 0, stream>>>(outf, out_w1, out_b1, tbuf, NGRAPH, D, D, 1);
    dim3 go((NGRAPH + BM - 1) / BM, (100 + BNT - 1) / BNT);
    gemm_kernel<<<go, 256, 0, stream>>>(tbuf, out_w2, out_b2, outf + (size_t)NGRAPH * D,
                                        NGRAPH, D, 100, 0);
    hipMemcpyAsync(outf + (size_t)NGRAPH * D + (size_t)NGRAPH * 100,
                   outf + (size_t)NGRAPH * D,
                   (size_t)NGRAPH * 100 * 4, hipMemcpyDeviceToDevice, stream);
}

// Round 4
// 2177.834 us; speedup vs baseline: 1.7914x; 1.1391x over previous
//
#include <hip/hip_runtime.h>

#define N_NODES 50000
#define N_EDGES 200000
#define D 200
#define NLAYERS 10
#define NGRAPH 2500
#define EPS 1e-5f

typedef unsigned short u16;
typedef unsigned int u32;
typedef __attribute__((ext_vector_type(8))) __bf16 bf16x8;
typedef __attribute__((ext_vector_type(4))) float f32x4;

// fp32 -> bf16 RNE
__device__ __forceinline__ u16 f2bf_rne(float x) {
    union { float f; unsigned u; } c; c.f = x;
    unsigned r = c.u + 0x7FFF + ((c.u >> 16) & 1);
    return (u16)(r >> 16);
}
// packed: low u16 = hi bf16, high u16 = lo bf16
__device__ __forceinline__ u32 split_pack(float x) {
    u16 h = f2bf_rne(x);
    union { unsigned u; float f; } c; c.u = ((unsigned)h) << 16;
    u16 l = f2bf_rne(x - c.f);
    return (u32)h | ((u32)l << 16);
}

// ---------------- CSR build -------------------------------------------------

__global__ void count_kernel(const int* __restrict__ dst, int* __restrict__ counts) {
    int e = blockIdx.x * 256 + threadIdx.x;
    if (e < N_EDGES) atomicAdd(&counts[dst[e]], 1);
}

__global__ void scan1_kernel(const int* __restrict__ counts, int* __restrict__ psum) {
    __shared__ int s[256];
    int idx = blockIdx.x * 256 + threadIdx.x;
    s[threadIdx.x] = (idx < N_NODES) ? counts[idx] : 0;
    __syncthreads();
    for (int off = 128; off > 0; off >>= 1) {
        if (threadIdx.x < off) s[threadIdx.x] += s[threadIdx.x + off];
        __syncthreads();
    }
    if (threadIdx.x == 0) psum[blockIdx.x] = s[0];
}

__global__ void scan2_kernel(const int* __restrict__ psum, int* __restrict__ poff, int nchunk) {
    __shared__ int s[256];
    int t = threadIdx.x;
    int v = (t < nchunk) ? psum[t] : 0;
    s[t] = v;
    __syncthreads();
    for (int off = 1; off < 256; off <<= 1) {
        int xv = (t >= off) ? s[t - off] : 0;
        __syncthreads();
        s[t] += xv;
        __syncthreads();
    }
    if (t < nchunk) poff[t] = s[t] - v;
}

__global__ void scan3_kernel(const int* __restrict__ counts, const int* __restrict__ poff,
                             int* __restrict__ row_start, int* __restrict__ cursor) {
    __shared__ int s[256];
    int t = threadIdx.x;
    int idx = blockIdx.x * 256 + t;
    int v = (idx < N_NODES) ? counts[idx] : 0;
    s[t] = v;
    __syncthreads();
    for (int off = 1; off < 256; off <<= 1) {
        int xv = (t >= off) ? s[t - off] : 0;
        __syncthreads();
        s[t] += xv;
        __syncthreads();
    }
    if (idx < N_NODES) {
        int rs = poff[blockIdx.x] + s[t] - v;
        row_start[idx] = rs;
        cursor[idx] = rs;
    }
    if (blockIdx.x == 0 && t == 0) row_start[N_NODES] = N_EDGES;
}

__global__ void scatter_kernel(const int* __restrict__ dst, int* __restrict__ cursor,
                               int* __restrict__ edge_list) {
    int e = blockIdx.x * 256 + threadIdx.x;
    if (e < N_EDGES) {
        int p = atomicAdd(&cursor[dst[e]], 1);
        edge_list[p] = e;
    }
}

__global__ void bounds_kernel(const int* __restrict__ batch, int* __restrict__ gstart) {
    int g = blockIdx.x * 256 + threadIdx.x;
    if (g > NGRAPH) return;
    if (g == NGRAPH) { gstart[NGRAPH] = N_NODES; return; }
    int lo = 0, hi = N_NODES;
    while (lo < hi) { int mid = (lo + hi) >> 1; if (batch[mid] < g) lo = mid + 1; else hi = mid; }
    gstart[g] = lo;
}

// ---------------- weight prep: transpose + pad + packed hi/lo bf16 -----------
// Wt1p: [L][512][224] u32  (row = output col n of W1, col = k)
// Wt2p: [L][256][416] u32

__global__ void prep_w1_kernel(const float* __restrict__ w, u32* __restrict__ wp) {
    int idx = blockIdx.x * 256 + threadIdx.x;
    if (idx >= NLAYERS * 512 * 224) return;
    int k = idx % 224;
    int n = (idx / 224) % 512;
    int l = idx / (224 * 512);
    float v = (k < 200 && n < 400) ? w[((size_t)l * 200 + k) * 400 + n] : 0.f;
    wp[idx] = split_pack(v);
}

__global__ void prep_w2_kernel(const float* __restrict__ w, u32* __restrict__ wp) {
    int idx = blockIdx.x * 256 + threadIdx.x;
    if (idx >= NLAYERS * 256 * 416) return;
    int k = idx % 416;
    int n = (idx / 416) % 256;
    int l = idx / (416 * 256);
    float v = (k < 400 && n < 200) ? w[((size_t)l * 400 + k) * 200 + n] : 0.f;
    wp[idx] = split_pack(v);
}

// ---------------- node feature init ------------------------------------------

__global__ void embed_kernel(const int* __restrict__ x, const float* __restrict__ emb1,
                             const float* __restrict__ emb2, float* __restrict__ h) {
    int idx = blockIdx.x * 256 + threadIdx.x;
    if (idx >= N_NODES * 50) return;
    int node = idx / 50;
    int c = (idx % 50) * 4;
    int a = x[node * 2], b = x[node * 2 + 1];
    float4 v1 = *(const float4*)(emb1 + (size_t)a * D + c);
    float4 v2 = *(const float4*)(emb2 + (size_t)b * D + c);
    float4 o;
    o.x = v1.x + v2.x; o.y = v1.y + v2.y; o.z = v1.z + v2.z; o.w = v1.w + v2.w;
    *(float4*)(h + (size_t)node * D + c) = o;
}

// ---------------- message + aggregate (+fused BN-norm+ReLU of prev layer) ----

template <int HAS_BN>
__global__ void aggregate_kernel(const float* __restrict__ hin,
                                 const float* __restrict__ stats,
                                 const float* __restrict__ gamma, const float* __restrict__ beta,
                                 const float* __restrict__ e1, const float* __restrict__ e2,
                                 const int* __restrict__ row_start, const int* __restrict__ edge_list,
                                 const int* __restrict__ src, const int* __restrict__ edge_attr,
                                 u32* __restrict__ Ap) {
    __shared__ float t1[5 * D];
    __shared__ float t2[3 * D];
    for (int i = threadIdx.x; i < 5 * D; i += 256) t1[i] = e1[i];
    for (int i = threadIdx.x; i < 3 * D; i += 256) t2[i] = e2[i];
    __syncthreads();
    int idx = blockIdx.x * 256 + threadIdx.x;
    if (idx >= N_NODES * 56) return;
    int node = idx / 56;
    int c = (idx % 56) * 4;
    size_t ob = (size_t)node * 224 + c;
    if (c >= 200) {  // K padding
        *(uint4*)(Ap + ob) = make_uint4(0u, 0u, 0u, 0u);
        return;
    }
    float a[4], b[4];
    if (HAS_BN) {
        const float invN = 1.0f / (float)N_NODES;
#pragma unroll
        for (int j = 0; j < 4; ++j) {
            float s = stats[c + j], q = stats[256 + c + j];
            float m = s * invN;
            float var = q * invN - m * m;
            float sc = gamma[c + j] * rsqrtf(var + EPS);
            a[j] = sc; b[j] = beta[c + j] - m * sc;
        }
    }
    float4 acc = *(const float4*)(hin + (size_t)node * D + c);
    if (HAS_BN) {
        acc.x = fmaxf(acc.x * a[0] + b[0], 0.f);
        acc.y = fmaxf(acc.y * a[1] + b[1], 0.f);
        acc.z = fmaxf(acc.z * a[2] + b[2], 0.f);
        acc.w = fmaxf(acc.w * a[3] + b[3], 0.f);
    }
    acc.x += t1[4 * D + c + 0] + t2[c + 0];
    acc.y += t1[4 * D + c + 1] + t2[c + 1];
    acc.z += t1[4 * D + c + 2] + t2[c + 2];
    acc.w += t1[4 * D + c + 3] + t2[c + 3];
    int jb = row_start[node], je = row_start[node + 1];
    for (int j = jb; j < je; ++j) {
        int e = edge_list[j];
        int s = src[e];
        int2 eav = *(const int2*)(edge_attr + 2 * e);
        float4 hv = *(const float4*)(hin + (size_t)s * D + c);
        if (HAS_BN) {
            hv.x = fmaxf(hv.x * a[0] + b[0], 0.f);
            hv.y = fmaxf(hv.y * a[1] + b[1], 0.f);
            hv.z = fmaxf(hv.z * a[2] + b[2], 0.f);
            hv.w = fmaxf(hv.w * a[3] + b[3], 0.f);
        }
        const float* p1 = t1 + eav.x * D + c;
        const float* p2 = t2 + eav.y * D + c;
        acc.x += hv.x + p1[0] + p2[0];
        acc.y += hv.y + p1[1] + p2[1];
        acc.z += hv.z + p1[2] + p2[2];
        acc.w += hv.w + p1[3] + p2[3];
    }
    uint4 pv;
    pv.x = split_pack(acc.x); pv.y = split_pack(acc.y);
    pv.z = split_pack(acc.z); pv.w = split_pack(acc.w);
    *(uint4*)(Ap + ob) = pv;
}

// ---------------- bf16x2 MFMA GEMM, 128x128 tile, packed u32 hi/lo -----------
// C[M,Nc] = A[M,Kpad] @ Wt[Nc',Kpad]^T + bias. 3-term hi/lo bf16 from packed.
// 4 waves (2x2), wave tile 64x64, K-step 32, 16x16x32 MFMA.
// LDS swizzle: elem offset(row, g) = row*32 + (g ^ ((row>>1)&3))*8 (0 conflicts)

template <int RELU, int WRITE_PACKED, int STATS>
__global__ __launch_bounds__(256) void gemm_mfma(
    const u32* __restrict__ Ap, const u32* __restrict__ Bp,
    const float* __restrict__ bias,
    float* __restrict__ Cf, u32* __restrict__ Cp,
    float* __restrict__ stats,
    int M, int Kpad, int Nc, int NcPad, int KT)
{
    __shared__ alignas(16) u16 sAh[128 * 32];
    __shared__ alignas(16) u16 sAl[128 * 32];
    __shared__ alignas(16) u16 sBh[128 * 32];
    __shared__ alignas(16) u16 sBl[128 * 32];

    const int tid = threadIdx.x;
    const int lane = tid & 63;
    const int wid = tid >> 6;
    const int wm = wid >> 1, wn = wid & 1;
    const int lr = lane & 15, lg = lane >> 4;
    const int bm0 = blockIdx.y * 128;
    const int bn0 = blockIdx.x * 128;

    const int r0 = tid >> 2;
    const int gd = tid & 3;
    const int slot = gd ^ ((r0 >> 1) & 3);
    const int lO0 = r0 * 32 + slot * 8;
    const int lO1 = lO0 + 64 * 32;
    const size_t gA0 = (size_t)(bm0 + r0) * Kpad + gd * 8;
    const size_t gA1 = gA0 + (size_t)64 * Kpad;
    const size_t gB0 = (size_t)(bn0 + r0) * Kpad + gd * 8;
    const size_t gB1 = gB0 + (size_t)64 * Kpad;

    f32x4 acc[4][4];
#pragma unroll
    for (int i = 0; i < 4; ++i)
#pragma unroll
        for (int j = 0; j < 4; ++j) acc[i][j] = (f32x4){0.f, 0.f, 0.f, 0.f};

    int aoff[4], boff[4];
#pragma unroll
    for (int f = 0; f < 4; ++f) {
        int arow = wm * 64 + f * 16 + lr;
        aoff[f] = arow * 32 + ((lg ^ ((arow >> 1) & 3)) * 8);
        int brow = wn * 64 + f * 16 + lr;
        boff[f] = brow * 32 + ((lg ^ ((brow >> 1) & 3)) * 8);
    }

    uint4 pA0a, pA0b, pA1a, pA1b, pB0a, pB0b, pB1a, pB1b;
#define LOADT(K0)                                            \
    pA0a = *(const uint4*)(Ap + gA0 + (K0));                 \
    pA0b = *(const uint4*)(Ap + gA0 + (K0) + 4);             \
    pA1a = *(const uint4*)(Ap + gA1 + (K0));                 \
    pA1b = *(const uint4*)(Ap + gA1 + (K0) + 4);             \
    pB0a = *(const uint4*)(Bp + gB0 + (K0));                 \
    pB0b = *(const uint4*)(Bp + gB0 + (K0) + 4);             \
    pB1a = *(const uint4*)(Bp + gB1 + (K0));                 \
    pB1b = *(const uint4*)(Bp + gB1 + (K0) + 4);

#define UNPACK_STORE(a, b, ph, pl)                                        \
    {                                                                     \
        uint4 hh, ll;                                                     \
        hh.x = __byte_perm((a).x, (a).y, 0x5410);                         \
        hh.y = __byte_perm((a).z, (a).w, 0x5410);                         \
        hh.z = __byte_perm((b).x, (b).y, 0x5410);                         \
        hh.w = __byte_perm((b).z, (b).w, 0x5410);                         \
        ll.x = __byte_perm((a).x, (a).y, 0x7632);                         \
        ll.y = __byte_perm((a).z, (a).w, 0x7632);                         \
        ll.z = __byte_perm((b).x, (b).y, 0x7632);                         \
        ll.w = __byte_perm((b).z, (b).w, 0x7632);                         \
        *(uint4*)(ph) = hh;                                               \
        *(uint4*)(pl) = ll;                                               \
    }

    LOADT(0)
    for (int kt = 0; kt < KT; ++kt) {
        if (kt > 0) __syncthreads();
        UNPACK_STORE(pA0a, pA0b, sAh + lO0, sAl + lO0)
        UNPACK_STORE(pA1a, pA1b, sAh + lO1, sAl + lO1)
        UNPACK_STORE(pB0a, pB0b, sBh + lO0, sBl + lO0)
        UNPACK_STORE(pB1a, pB1b, sBh + lO1, sBl + lO1)
        __syncthreads();
        if (kt + 1 < KT) { LOADT((size_t)(kt + 1) * 32) }

        bf16x8 fbh[4], fbl[4];
#pragma unroll
        for (int fn = 0; fn < 4; ++fn) {
            fbh[fn] = *(const bf16x8*)(sBh + boff[fn]);
            fbl[fn] = *(const bf16x8*)(sBl + boff[fn]);
        }
#pragma unroll
        for (int fm = 0; fm < 4; ++fm) {
            bf16x8 fah = *(const bf16x8*)(sAh + aoff[fm]);
            bf16x8 fal = *(const bf16x8*)(sAl + aoff[fm]);
#pragma unroll
            for (int fn = 0; fn < 4; ++fn) {
                acc[fm][fn] = __builtin_amdgcn_mfma_f32_16x16x32_bf16(fah, fbh[fn], acc[fm][fn], 0, 0, 0);
                acc[fm][fn] = __builtin_amdgcn_mfma_f32_16x16x32_bf16(fah, fbl[fn], acc[fm][fn], 0, 0, 0);
                acc[fm][fn] = __builtin_amdgcn_mfma_f32_16x16x32_bf16(fal, fbh[fn], acc[fm][fn], 0, 0, 0);
            }
        }
    }
#undef LOADT
#undef UNPACK_STORE

    // epilogue: frag D row = lg*4+r, col = lr
#pragma unroll
    for (int fn = 0; fn < 4; ++fn) {
        int col = bn0 + wn * 64 + fn * 16 + lr;
        float bv = (col < Nc) ? bias[col] : 0.f;
        if (WRITE_PACKED) {
            if (col < NcPad) {
#pragma unroll
                for (int fm = 0; fm < 4; ++fm) {
#pragma unroll
                    for (int r = 0; r < 4; ++r) {
                        int row = bm0 + wm * 64 + fm * 16 + lg * 4 + r;
                        if (row < M) {
                            float v = acc[fm][fn][r] + bv;
                            if (RELU) v = fmaxf(v, 0.f);
                            if (col >= Nc) v = 0.f;   // h1 K-padding cols must be 0
                            Cp[(size_t)row * NcPad + col] = split_pack(v);
                        }
                    }
                }
            }
        } else {
            float s = 0.f, q = 0.f;
#pragma unroll
            for (int fm = 0; fm < 4; ++fm) {
#pragma unroll
                for (int r = 0; r < 4; ++r) {
                    int row = bm0 + wm * 64 + fm * 16 + lg * 4 + r;
                    if (row < M && col < Nc) {
                        float v = acc[fm][fn][r] + bv;
                        if (RELU) v = fmaxf(v, 0.f);
                        Cf[(size_t)row * Nc + col] = v;
                        if (STATS) { s += v; q += v * v; }
                    }
                }
            }
            if (STATS) {
                s += __shfl_xor(s, 16); s += __shfl_xor(s, 32);
                q += __shfl_xor(q, 16); q += __shfl_xor(q, 32);
                if (lg == 0 && col < Nc) {
                    atomicAdd(&stats[col], s);
                    atomicAdd(&stats[256 + col], q);
                }
            }
        }
    }
}

// ---------------- fp32 tiled GEMM (tail, small M) ----------------------------

#define BM 128
#define BNT 64
#define BK 8

__global__ __launch_bounds__(256) void gemm_kernel(const float* __restrict__ A,
                                                   const float* __restrict__ W,
                                                   const float* __restrict__ bias,
                                                   float* __restrict__ C,
                                                   int M, int K, int Nc, int relu) {
    __shared__ float As[BK][BM];
    __shared__ float Bs[BK][BNT];
    int tid = threadIdx.x;
    int bm = blockIdx.x * BM;
    int bn = blockIdx.y * BNT;
    int tx = tid & 15, ty = tid >> 4;

    float acc[8][4];
#pragma unroll
    for (int i = 0; i < 8; ++i)
#pragma unroll
        for (int j = 0; j < 4; ++j) acc[i][j] = 0.f;

    int ar = tid >> 1;
    int ak = (tid & 1) << 2;
    int bk = tid >> 5;
    int bcol = (tid & 31) << 1;

    for (int k0 = 0; k0 < K; k0 += BK) {
        float4 av = {0.f, 0.f, 0.f, 0.f};
        int row = bm + ar;
        if (row < M) av = *(const float4*)(A + (size_t)row * K + k0 + ak);
        As[ak + 0][ar] = av.x; As[ak + 1][ar] = av.y;
        As[ak + 2][ar] = av.z; As[ak + 3][ar] = av.w;
        float2 bv = {0.f, 0.f};
        int col = bn + bcol;
        if (col < Nc) bv = *(const float2*)(W + (size_t)(k0 + bk) * Nc + col);
        Bs[bk][bcol] = bv.x; Bs[bk][bcol + 1] = bv.y;
        __syncthreads();
#pragma unroll
        for (int kk = 0; kk < BK; ++kk) {
            float a[8], b[4];
            *(float4*)(a)     = *(const float4*)(&As[kk][ty * 8]);
            *(float4*)(a + 4) = *(const float4*)(&As[kk][ty * 8 + 4]);
            *(float4*)(b)     = *(const float4*)(&Bs[kk][tx * 4]);
#pragma unroll
            for (int i = 0; i < 8; ++i)
#pragma unroll
                for (int j = 0; j < 4; ++j) acc[i][j] = fmaf(a[i], b[j], acc[i][j]);
        }
        __syncthreads();
    }

#pragma unroll
    for (int i = 0; i < 8; ++i) {
        int row = bm + ty * 8 + i;
        if (row < M) {
            int col = bn + tx * 4;
            if (col < Nc) {
                float4 bb = *(const float4*)(bias + col);
                float4 v;
                v.x = acc[i][0] + bb.x; v.y = acc[i][1] + bb.y;
                v.z = acc[i][2] + bb.z; v.w = acc[i][3] + bb.w;
                if (relu) {
                    v.x = fmaxf(v.x, 0.f); v.y = fmaxf(v.y, 0.f);
                    v.z = fmaxf(v.z, 0.f); v.w = fmaxf(v.w, 0.f);
                }
                *(float4*)(C + (size_t)row * Nc + col) = v;
            }
        }
    }
}

// ---------------- global mean pool (+fused BN of last layer, no relu) --------

__global__ void pool_bn_kernel(const float* __restrict__ g2, const float* __restrict__ stats,
                               const float* __restrict__ gamma, const float* __restrict__ beta,
                               const int* __restrict__ gstart, float* __restrict__ hg) {
    int idx = blockIdx.x * 256 + threadIdx.x;
    if (idx >= NGRAPH * 50) return;
    int g = idx / 50;
    int c = (idx % 50) * 4;
    float a[4], b[4];
    const float invN = 1.0f / (float)N_NODES;
#pragma unroll
    for (int j = 0; j < 4; ++j) {
        float s = stats[c + j], q = stats[256 + c + j];
        float m = s * invN;
        float var = q * invN - m * m;
        float sc = gamma[c + j] * rsqrtf(var + EPS);
        a[j] = sc; b[j] = beta[c + j] - m * sc;
    }
    int s0 = gstart[g], e0 = gstart[g + 1];
    float4 acc = {0.f, 0.f, 0.f, 0.f};
    for (int r = s0; r < e0; ++r) {
        float4 v = *(const float4*)(g2 + (size_t)r * D + c);
        acc.x += v.x; acc.y += v.y; acc.z += v.z; acc.w += v.w;
    }
    float inv = 1.0f / fmaxf((float)(e0 - s0), 1.0f);
    acc.x = acc.x * inv * a[0] + b[0];
    acc.y = acc.y * inv * a[1] + b[1];
    acc.z = acc.z * inv * a[2] + b[2];
    acc.w = acc.w * inv * a[3] + b[3];
    *(float4*)(hg + (size_t)g * D + c) = acc;
}

// ---------------- launch -------------------------------------------------------

extern "C" void kernel_launch(void* const* d_in, const int* in_sizes, int n_in,
                              void* d_out, int out_size, void* d_ws, size_t ws_size,
                              hipStream_t stream) {
    const int*   x       = (const int*)d_in[0];
    const int*   ei      = (const int*)d_in[1];
    const int*   ea      = (const int*)d_in[2];
    const int*   batch   = (const int*)d_in[3];
    const float* x_emb1  = (const float*)d_in[4];
    const float* x_emb2  = (const float*)d_in[5];
    const float* e1w     = (const float*)d_in[6];
    const float* e2w     = (const float*)d_in[7];
    const float* w1      = (const float*)d_in[8];
    const float* b1      = (const float*)d_in[9];
    const float* w2      = (const float*)d_in[10];
    const float* b2      = (const float*)d_in[11];
    const float* gamma   = (const float*)d_in[12];
    const float* beta    = (const float*)d_in[13];
    const float* feat_w  = (const float*)d_in[14];
    const float* feat_b  = (const float*)d_in[15];
    const float* out_w1  = (const float*)d_in[16];
    const float* out_b1  = (const float*)d_in[17];
    const float* out_w2  = (const float*)d_in[18];
    const float* out_b2  = (const float*)d_in[19];
    const int* src = ei;
    const int* dst = ei + N_EDGES;

    char* p = (char*)d_ws;
    auto alloc = [&](size_t bytes) -> void* {
        void* r = (void*)p;
        p += (bytes + 255) & ~(size_t)255;
        return r;
    };
    const int MPAD = 50048;                         // 391*128
    // h (layer-0 input) and g2 (raw GEMM2 output) share a buffer.
    float* h      = (float*)alloc((size_t)N_NODES * D * 4);          // 40 MB
    float* g2     = h;
    u32*   aggrP  = (u32*)alloc((size_t)MPAD * 224 * 4);             // 44.8 MB
    u32*   h1p    = (u32*)alloc((size_t)MPAD * 416 * 4);             // 83.3 MB
    u32*   wt1p   = (u32*)alloc((size_t)NLAYERS * 512 * 224 * 4);    // 4.6 MB
    u32*   wt2p   = (u32*)alloc((size_t)NLAYERS * 256 * 416 * 4);    // 4.3 MB
    int*   counts    = (int*)alloc(N_NODES * 4);
    int*   row_start = (int*)alloc((N_NODES + 1) * 4);
    int*   cursor    = (int*)alloc(N_NODES * 4);
    int*   edge_list = (int*)alloc(N_EDGES * 4);
    int*   psum      = (int*)alloc(256 * 4);
    int*   poff      = (int*)alloc(256 * 4);
    int*   gstart    = (int*)alloc((NGRAPH + 1) * 4);
    float* stats     = (float*)alloc(512 * 4);       // [sum 256][sumsq 256]
    float* hg        = (float*)alloc((size_t)NGRAPH * D * 4);
    float* tbuf      = (float*)alloc((size_t)NGRAPH * D * 4);
    float* outf      = (float*)d_out;

    const int NCHUNK = (N_NODES + 255) / 256;

    // weight prep (once per launch)
    prep_w1_kernel<<<(NLAYERS * 512 * 224 + 255) / 256, 256, 0, stream>>>(w1, wt1p);
    prep_w2_kernel<<<(NLAYERS * 256 * 416 + 255) / 256, 256, 0, stream>>>(w2, wt2p);

    // CSR build + graph bounds
    hipMemsetAsync(counts, 0, N_NODES * 4, stream);
    count_kernel<<<(N_EDGES + 255) / 256, 256, 0, stream>>>(dst, counts);
    scan1_kernel<<<NCHUNK, 256, 0, stream>>>(counts, psum);
    scan2_kernel<<<1, 256, 0, stream>>>(psum, poff, NCHUNK);
    scan3_kernel<<<NCHUNK, 256, 0, stream>>>(counts, poff, row_start, cursor);
    scatter_kernel<<<(N_EDGES + 255) / 256, 256, 0, stream>>>(dst, cursor, edge_list);
    bounds_kernel<<<(NGRAPH + 1 + 255) / 256, 256, 0, stream>>>(batch, gstart);

    embed_kernel<<<(N_NODES * 50 + 255) / 256, 256, 0, stream>>>(x, x_emb1, x_emb2, h);

    dim3 g1(4, 391);   // GEMM1: x = N-blocks (512 pad), y = M-blocks
    dim3 g2d(2, 391);  // GEMM2: x = N-blocks (256 pad)
    for (int l = 0; l < NLAYERS; ++l) {
        if (l == 0)
            aggregate_kernel<0><<<(N_NODES * 56 + 255) / 256, 256, 0, stream>>>(
                h, nullptr, nullptr, nullptr,
                e1w, e2w, row_start, edge_list, src, ea, aggrP);
        else
            aggregate_kernel<1><<<(N_NODES * 56 + 255) / 256, 256, 0, stream>>>(
                g2, stats, gamma + (size_t)(l - 1) * D, beta + (size_t)(l - 1) * D,
                e1w + (size_t)l * 5 * D, e2w + (size_t)l * 3 * D,
                row_start, edge_list, src, ea, aggrP);
        gemm_mfma<1, 1, 0><<<g1, 256, 0, stream>>>(
            aggrP, wt1p + (size_t)l * 512 * 224,
            b1 + (size_t)l * 400, nullptr, h1p, nullptr, N_NODES, 224, 400, 416, 7);
        hipMemsetAsync(stats, 0, 512 * 4, stream);
        gemm_mfma<0, 0, 1><<<g2d, 256, 0, stream>>>(
            h1p, wt2p + (size_t)l * 256 * 416,
            b2 + (size_t)l * 200, g2, nullptr, stats, N_NODES, 416, 200, 200, 13);
    }

    pool_bn_kernel<<<(NGRAPH * 50 + 255) / 256, 256, 0, stream>>>(
        g2, stats, gamma + (size_t)(NLAYERS - 1) * D, beta + (size_t)(NLAYERS - 1) * D,
        gstart, hg);

    dim3 gp((NGRAPH + BM - 1) / BM, (D + BNT - 1) / BNT);
    gemm_kernel<<<gp, 256, 0, stream>>>(hg, feat_w, feat_b, outf, NGRAPH, D, D, 0);
    gemm_kernel<<<gp, 256, 0, stream>>>(outf, out_w1, out_b1, tbuf, NGRAPH, D, D, 1);
    dim3 go((NGRAPH + BM - 1) / BM, (100 + BNT - 1) / BNT);
    gemm_kernel<<<go, 256, 0, stream>>>(tbuf, out_w2, out_b2, outf + (size_t)NGRAPH * D,
                                        NGRAPH, D, 100, 0);
    hipMemcpyAsync(outf + (size_t)NGRAPH * D + (size_t)NGRAPH * 100,
                   outf + (size_t)NGRAPH * D,
                   (size_t)NGRAPH * 100 * 4, hipMemcpyDeviceToDevice, stream);
}